// Round 7
// baseline (191.640 us; speedup 1.0000x reference)
//
#include <hip/hip_runtime.h>
#include <math.h>

#define Vc 5
#define Cc 32
#define Gc 8
#define Dc 32
#define Hc 192
#define Wc 192
#define HWc (Hc*Wc)
#define NSRC (Vc-1)
#define NTILE (HWc/64)   // 576

// output offsets (floats)
#define OFF_DEPTH  0
#define OFF_CONF   (HWc)
#define OFF_ATTN   (2*HWc)
#define OFF_EST    (OFF_ATTN + Dc*HWc)
#define OFF_SW     (OFF_EST + 3*HWc)
#define OFF_WEIGHT (OFF_SW + HWc)
#define OFF_NVAL   (OFF_WEIGHT + NSRC*HWc)
#define OFF_MIN    (OFF_NVAL + Dc*HWc)
#define OFF_MAX    (OFF_MIN + HWc)

// ws layout (floats):
//   [0]=hmin [1]=hmax (fallback path only)
//   [2 + i*15]: rot(9), trans(3), norv(3)
//   [T_OFF]: channels-last images, img=0..3 src, 4 ref, 5 depth ([HW][32] each)
//   [PART_OFF]: 576 partial (min,max) pairs from prep depth blocks
//   [NP_OFF]: normal_plane packed [HW][4]
#define T_OFF 64
#define PART_OFF (T_OFF + 6*Cc*HWc)
#define NP_OFF (PART_OFF + 2*NTILE)

__device__ void inv4(const float* A, float* out) {
    float M[4][8];
    for (int r = 0; r < 4; r++) {
        for (int c = 0; c < 4; c++) { M[r][c] = A[r*4+c]; M[r][c+4] = (r == c) ? 1.f : 0.f; }
    }
    for (int col = 0; col < 4; col++) {
        int piv = col; float best = fabsf(M[col][col]);
        for (int r = col+1; r < 4; r++) { float v = fabsf(M[r][col]); if (v > best) { best = v; piv = r; } }
        if (piv != col) for (int c = 0; c < 8; c++) { float t = M[col][c]; M[col][c] = M[piv][c]; M[piv][c] = t; }
        float inv = 1.f / M[col][col];
        for (int c = 0; c < 8; c++) M[col][c] *= inv;
        for (int r = 0; r < 4; r++) {
            if (r == col) continue;
            float f = M[r][col];
            for (int c = 0; c < 8; c++) M[r][c] -= f * M[col][c];
        }
    }
    for (int r = 0; r < 4; r++) for (int c = 0; c < 4; c++) out[r*4+c] = M[r][c+4];
}

__device__ void inv3(const float* A, float* out) {
    float a=A[0],b=A[1],c=A[2],d=A[3],e=A[4],f=A[5],g=A[6],h=A[7],i=A[8];
    float det = a*(e*i-f*h) - b*(d*i-f*g) + c*(d*h-e*g);
    float id = 1.f/det;
    out[0]=(e*i-f*h)*id; out[1]=(c*h-b*i)*id; out[2]=(b*f-c*e)*id;
    out[3]=(f*g-d*i)*id; out[4]=(a*i-c*g)*id; out[5]=(c*d-a*f)*id;
    out[6]=(d*h-e*g)*id; out[7]=(b*g-a*h)*id; out[8]=(a*e-b*d)*id;
}

__device__ void setup_body(const float* __restrict__ rotation,
                           const float* __restrict__ proj,
                           float* __restrict__ wsf) {
    float refE[16], refK[16], refNew[16], invRef[16];
    for (int k = 0; k < 16; k++) { refE[k] = proj[k]; refK[k] = proj[16+k]; }
    for (int k = 0; k < 16; k++) refNew[k] = refE[k];
    for (int r = 0; r < 3; r++) for (int c = 0; c < 4; c++) {
        float s = 0.f;
        for (int k = 0; k < 3; k++) s += refK[r*4+k] * refE[k*4+c];
        refNew[r*4+c] = s;
    }
    inv4(refNew, invRef);
    float invR0[9];
    inv3(rotation, invR0);

    for (int i = 0; i < NSRC; i++) {
        const float* E = proj + (i+1)*32;
        const float* K = proj + (i+1)*32 + 16;
        float sNew[16];
        for (int k = 0; k < 16; k++) sNew[k] = E[k];
        for (int r = 0; r < 3; r++) for (int c = 0; c < 4; c++) {
            float s = 0.f;
            for (int k = 0; k < 3; k++) s += K[r*4+k] * E[k*4+c];
            sNew[r*4+c] = s;
        }
        float P[16];
        for (int r = 0; r < 4; r++) for (int c = 0; c < 4; c++) {
            float s = 0.f;
            for (int k = 0; k < 4; k++) s += sNew[r*4+k] * invRef[k*4+c];
            P[r*4+c] = s;
        }
        float* o = wsf + 2 + i*15;
        for (int r = 0; r < 3; r++) for (int c = 0; c < 3; c++) o[r*3+c] = P[r*4+c];
        for (int r = 0; r < 3; r++) o[9+r] = P[r*4+3];
        const float* Ri = rotation + (i+1)*9;
        for (int c = 0; c < 3; c++) {
            float s = 0.f;
            for (int k = 0; k < 3; k++) s += Ri[2*3+k] * invR0[k*3+c];
            o[12+c] = s;
        }
    }
}

// Fused prep:
//  img 0..3: src [C][HW]->[HW][C];  img 4: ref;  img 5: depth (+ partial
//  min/max, plain stores -> no atomics, no memset init);  img 6: normal_plane
//  packed [HW][4]. Matrix setup rides on block (0, img0) thread 0.
__global__ __launch_bounds__(256)
void prep_kernel(const float* __restrict__ src,
                 const float* __restrict__ ref,
                 const float* __restrict__ depth,
                 const float* __restrict__ normal,
                 const float* __restrict__ rotation,
                 const float* __restrict__ proj,
                 float* __restrict__ wsf) {
    const int img = blockIdx.y;          // 0..6
    const int p0  = blockIdx.x * 64;
    const int t = threadIdx.x;

    if (img == 6) {  // normal_plane [3][HW] -> [HW][4]
        __shared__ float tl[3][64];
        if (t < 192) { const int c = t >> 6, p = t & 63; tl[c][p] = normal[c*HWc + p0 + p]; }
        __syncthreads();
        const int p = t >> 2, c = t & 3;
        wsf[NP_OFF + (size_t)(p0 + p)*4 + c] = (c < 3) ? tl[c][p] : 0.f;
        return;
    }

    const float* in = (img < NSRC) ? (src + (size_t)img*Cc*HWc)
                    : (img == NSRC) ? ref : depth;
    float* outp = wsf + T_OFF + (size_t)img * Cc * HWc;
    __shared__ float tile[Cc][64+1];
    float mn = __uint_as_float(0x7F800000u);
    float mx = 0.f;
#pragma unroll
    for (int k = 0; k < 8; k++) {
        const int c = (t >> 6) + k*4;
        const int p = t & 63;
        const float v = in[(size_t)c*HWc + p0 + p];
        tile[c][p] = v;
        mn = fminf(mn, v);
        mx = fmaxf(mx, v);
    }
    __syncthreads();
#pragma unroll
    for (int k = 0; k < 8; k++) {
        const int c = t & 31;
        const int p = (t >> 5) + k*8;
        outp[(size_t)(p0 + p)*Cc + c] = tile[c][p];
    }
    if (img == 5) {   // depth tile: partial min/max, one pair per block
        for (int off = 32; off; off >>= 1) {
            mn = fminf(mn, __shfl_xor(mn, off));
            mx = fmaxf(mx, __shfl_xor(mx, off));
        }
        __shared__ float smn[4], smx[4];
        const int w = t >> 6;
        if ((t & 63) == 0) { smn[w] = mn; smx[w] = mx; }
        __syncthreads();
        if (t == 0) {
            for (int i = 1; i < 4; i++) { mn = fminf(mn, smn[i]); mx = fmaxf(mx, smx[i]); }
            wsf[PART_OFF + blockIdx.x*2 + 0] = mn;
            wsf[PART_OFF + blockIdx.x*2 + 1] = mx;
        }
    }
    if (img == 0 && blockIdx.x == 0 && t == 0)
        setup_body(rotation, proj, wsf);
}

// Bilinear weight + BYTE tap-offset computation (uses Wv[0..11] only).
// Byte offsets (cell*128) enable 32-bit saddr-form gathers in phase 2.
__device__ __forceinline__ void compute_wo(float fxp, float fyp, const float* __restrict__ Wv,
                                           float dep, float4* wout, int4* oout) {
    const float b0 = Wv[0]*fxp + Wv[1]*fyp + Wv[2];
    const float b1 = Wv[3]*fxp + Wv[4]*fyp + Wv[5];
    const float b2 = Wv[6]*fxp + Wv[7]*fyp + Wv[8];
    float z = fmaf(b2, dep, Wv[11]);
    if (z == 0.f) z = 1e-9f;
    float rz = __builtin_amdgcn_rcpf(z);
    rz = rz * (2.f - z * rz);                 // Newton refine
    const float px = fmaf(b0, dep, Wv[9])  * rz;
    const float py = fmaf(b1, dep, Wv[10]) * rz;

    const float fx0 = floorf(px), fy0 = floorf(py);
    const float wx = px - fx0, wy = py - fy0;
    const float fx1 = fx0 + 1.f, fy1 = fy0 + 1.f;
    const bool ix0 = (fx0 >= 0.f) && (fx0 <= (float)(Wc-1));
    const bool ix1 = (fx1 >= 0.f) && (fx1 <= (float)(Wc-1));
    const bool iy0 = (fy0 >= 0.f) && (fy0 <= (float)(Hc-1));
    const bool iy1 = (fy1 >= 0.f) && (fy1 <= (float)(Hc-1));
    const float w00 = (1.f-wx)*(1.f-wy) * ((ix0 && iy0) ? 1.f : 0.f);
    const float w10 = wx*(1.f-wy)       * ((ix1 && iy0) ? 1.f : 0.f);
    const float w01 = (1.f-wx)*wy       * ((ix0 && iy1) ? 1.f : 0.f);
    const float w11 = wx*wy             * ((ix1 && iy1) ? 1.f : 0.f);
    const int xi0 = (int)fminf(fmaxf(fx0, 0.f), (float)(Wc-1));
    const int xi1 = (int)fminf(fmaxf(fx1, 0.f), (float)(Wc-1));
    const int yi0 = (int)fminf(fmaxf(fy0, 0.f), (float)(Hc-1));
    const int yi1 = (int)fminf(fmaxf(fy1, 0.f), (float)(Hc-1));
    *wout = make_float4(w00, w10, w01, w11);
    *oout = make_int4((yi0*Wc + xi0) << 7, (yi0*Wc + xi1) << 7,
                      (yi1*Wc + xi0) << 7, (yi1*Wc + xi1) << 7);   // BYTES
}

// 1-pixel / 128-thread / 2-wave main kernel.
// Rationale (R6 post-mortem): kernel is barrier/dependency-stall-bound, not
// issue-bound. Halving the sync domain doubles independent blocks per CU
// (16 blocks = 32 waves at ~6.3KB LDS) so stalled barriers overlap.
//  phase 1 (dense): 128 lanes = (view, d) weight compute; wave1 + minmax
//  phase 2: per thread 2 d-values x 4 views x 4 taps = 32 saddr gathers
//  phase 3 (dense): 128 lanes = (view, d) softmax + srcw + sims
//  phase 4: accumulate, logits; epilogue on wave0 lanes <32.
template<bool USE_NPT>
__global__ __launch_bounds__(128, 8)
void main_kernel_t(const float* __restrict__ normal_plane,
                   const float* __restrict__ w_reg,
                   const float* __restrict__ w_norm,
                   const float* __restrict__ wsf,
                   float* __restrict__ out) {
    // bijective XCD swizzle: consecutive pix co-resident per XCD
    const int bid = blockIdx.x;
    const int pix = (bid & 7) * (HWc/8) + (bid >> 3);
    const int t = threadIdx.x;      // 0..127
    const int g = t & 7;
    const int dh = t >> 3;          // 0..15 (thread also handles dh+16)
    const int wv = t >> 6;          // wave 0/1
    const int wl = t & 63;
    const float fxp = (float)(pix % Wc);
    const float fyp = (float)(pix / Wc);

    const char*   srcB = (const char*)(wsf + T_OFF);
    const float4* refT = (const float4*)(wsf + T_OFF + (size_t)4*Cc*HWc);
    const float*  depT = wsf + T_OFF + (size_t)5*Cc*HWc;

    __shared__ float4 s_wt[NSRC][Dc];
    __shared__ int4   s_of[NSRC][Dc];
    __shared__ float  s_sd[NSRC][Dc];
    __shared__ float  s_val[NSRC][Dc];
    __shared__ float  s_w[NSRC][Dc];
    __shared__ float  s_sw[NSRC][Dc];
    __shared__ float  s_lg[Dc];
    __shared__ float  s_hmm[2];

    // prologue: ref fragment (1 float4), packed normal, depths
    float4 rv = refT[pix*8 + g];
    rv.x *= 0.25f; rv.y *= 0.25f; rv.z *= 0.25f; rv.w *= 0.25f;
    float4 npv;
    if (USE_NPT) {
        npv = ((const float4*)(wsf + NP_OFF))[pix];
    } else {
        npv = make_float4(normal_plane[pix], normal_plane[HWc+pix],
                          normal_plane[2*HWc+pix], 0.f);
    }
    const float dep_d0 = depT[(size_t)pix*Dc + dh];
    const float dep_d1 = depT[(size_t)pix*Dc + dh + 16];
    const float wreg_g = w_reg[g];

    // ---- phase 1 (dense): lane -> (view, d); wave1 also reduces minmax ----
    {
        const int vvv = (wv << 1) | (wl >> 5);
        const int dd = wl & 31;
        const float* Wa = wsf + 2 + (wv << 1)*15;
        const float* Wb = Wa + 15;
        float Wv[12];
#pragma unroll
        for (int k = 0; k < 12; k++) Wv[k] = (wl < 32) ? Wa[k] : Wb[k];
        compute_wo(fxp, fyp, Wv, depT[(size_t)pix*Dc + dd],
                   &s_wt[vvv][dd], &s_of[vvv][dd]);
        if (wv == 1) {   // reduce 576 partial (min,max) pairs
            float mn = __uint_as_float(0x7F800000u);
            float mx = 0.f;
#pragma unroll
            for (int j = 0; j < 9; j++) {   // 576 = 64*9
                mn = fminf(mn, wsf[PART_OFF + (wl + 64*j)*2 + 0]);
                mx = fmaxf(mx, wsf[PART_OFF + (wl + 64*j)*2 + 1]);
            }
            for (int off = 32; off; off >>= 1) {
                mn = fminf(mn, __shfl_xor(mn, off));
                mx = fmaxf(mx, __shfl_xor(mx, off));
            }
            if (wl == 0) { s_hmm[0] = mn; s_hmm[1] = mx; }
        }
    }
    __syncthreads();

    // ---- phase 2: 32 saddr gathers (2 d x 4 views x 4 taps), full ILP ----
    float corfeat[2][NSRC];
    const unsigned gb = (unsigned)(g << 4);
#pragma unroll
    for (int dx = 0; dx < 2; dx++) {
        const int d = dh + dx*16;
#pragma unroll
        for (int i = 0; i < NSRC; i++) {
            const float4 wv4 = s_wt[i][d];
            const int4   ov  = s_of[i][d];
            const char* sp = srcB + (size_t)i*(Cc*HWc*4);
            const float4 v00 = *(const float4*)(sp + ((unsigned)ov.x + gb));
            const float4 v10 = *(const float4*)(sp + ((unsigned)ov.y + gb));
            const float4 v01 = *(const float4*)(sp + ((unsigned)ov.z + gb));
            const float4 v11 = *(const float4*)(sp + ((unsigned)ov.w + gb));
            const float bx = wv4.x*v00.x + wv4.y*v10.x + wv4.z*v01.x + wv4.w*v11.x;
            const float by = wv4.x*v00.y + wv4.y*v10.y + wv4.z*v01.y + wv4.w*v11.y;
            const float bz = wv4.x*v00.z + wv4.y*v10.z + wv4.z*v01.z + wv4.w*v11.z;
            const float bw = wv4.x*v00.w + wv4.y*v10.w + wv4.z*v01.w + wv4.w*v11.w;
            corfeat[dx][i] = bx*rv.x + by*rv.y + bz*rv.z + bw*rv.w;

            float sd = corfeat[dx][i];
            sd += __shfl_xor(sd, 1);
            sd += __shfl_xor(sd, 2);
            sd += __shfl_xor(sd, 4);

            if (g == 0) { s_sd[i][d] = sd; s_val[i][d] = (bx != 0.f) ? 1.f : 0.f; }
        }
    }
    __syncthreads();

    // ---- phase 3 (dense): lane -> (view, d) softmax + srcw + sims ----
    {
        const int vvv = (wv << 1) | (wl >> 5);
        const int dd = wl & 31;
        const float u = s_sd[vvv][dd];
        float m = u;
        for (int off = 1; off < 32; off <<= 1) m = fmaxf(m, __shfl_xor(m, off));
        const float e = __expf(u - m);
        float se = e;
        for (int off = 1; off < 32; off <<= 1) se += __shfl_xor(se, off);
        float rse = __builtin_amdgcn_rcpf(se);
        rse = rse * (2.f - se * rse);
        s_w[vvv][dd] = e * rse * 0.17677669529663687f;  // softmax / sqrt(C)

        const float* Na = wsf + 2 + (wv << 1)*15 + 12;
        const float* Nb = Na + 15;
        const float n0 = (wl < 32) ? Na[0] : Nb[0];
        const float n1 = (wl < 32) ? Na[1] : Nb[1];
        const float n2 = (wl < 32) ? Na[2] : Nb[2];
        const float srcw_v = fmaxf(npv.x*n0 + npv.y*n1 + npv.z*n2, 0.f) + 0.01f;
        const float swv = srcw_v * s_val[vvv][dd];
        s_sw[vvv][dd] = swv;
        float ss = swv;
        for (int off = 1; off < 32; off <<= 1) ss += __shfl_xor(ss, off);
        if ((wl & 31) == 0) out[OFF_WEIGHT + vvv*HWc + pix] = ss * (1.f/32.f);
    }
    __syncthreads();

    // ---- phase 4: accumulate + logits (2 d per thread) ----
    const float hmin = s_hmm[0];
    const float hmax = s_hmm[1];
    const float hr = hmax - hmin;
    float rhr = __builtin_amdgcn_rcpf(hr);
    rhr = rhr * (2.f - hr * rhr);

#pragma unroll
    for (int dx = 0; dx < 2; dx++) {
        const int d = dh + dx*16;
        float acc_cor = 0.f;
        float cws_acc = 1e-8f;
        float sumw_acc = 1e-8f;
#pragma unroll
        for (int i = 0; i < NSRC; i++) {
            const float cor_w = s_w[i][d];
            const float sw = s_sw[i][d];
            acc_cor = fmaf(cor_w * sw, corfeat[dx][i], acc_cor);
            cws_acc += cor_w;
            sumw_acc += sw;
        }
        float r1 = __builtin_amdgcn_rcpf(sumw_acc);
        r1 = r1 * (2.f - sumw_acc * r1);
        float r2 = __builtin_amdgcn_rcpf(cws_acc);
        r2 = r2 * (2.f - cws_acc * r2);
        const float cf_final = acc_cor * r1 * r2;
        float part = cf_final * wreg_g;
        part += __shfl_xor(part, 1);
        part += __shfl_xor(part, 2);
        part += __shfl_xor(part, 4);
        const float dd_ = dx ? dep_d1 : dep_d0;
        const float logit = part + (dd_ - hmin) * rhr;
        if (g == 0) s_lg[d] = logit;
        if (t == 0 && dx == 0) out[OFF_SW + pix] = sumw_acc * 0.25f;  // d==0
    }
    __syncthreads();

    // ---- epilogue: wave0 lanes<32 -> attn/argmax; wave1 lanes<3 -> est ----
    if (t < 32) {
        const float L = s_lg[t];
        float m = L;
        for (int off = 1; off < 32; off <<= 1) m = fmaxf(m, __shfl_xor(m, off));
        const float e = __expf(L - m);
        float se = e;
        for (int off = 1; off < 32; off <<= 1) se += __shfl_xor(se, off);
        float rse = __builtin_amdgcn_rcpf(se);
        rse = rse * (2.f - se * rse);
        const float attn = e * rse;

        const float nval = s_val[0][t] + s_val[1][t] + s_val[2][t] + s_val[3][t];
        out[OFF_ATTN + t*HWc + pix] = attn;
        out[OFF_NVAL + t*HWc + pix] = nval;

        float av = attn; int ai = t;
        for (int off = 1; off < 32; off <<= 1) {
            float av2 = __shfl_xor(av, off);
            int ai2 = __shfl_xor(ai, off);
            if (av2 > av || (av2 == av && ai2 < ai)) { av = av2; ai = ai2; }
        }
        const float dep = depT[(size_t)pix*Dc + t];
        const float dep_sel = __shfl(dep, ai);
        const float dep0 = __shfl(dep, 0);
        const float dep1 = __shfl(dep, 1);
        if (t == 0) {
            const float last_itv = dep1 - dep0;
            out[OFF_DEPTH + pix] = dep_sel;
            out[OFF_CONF + pix] = av;
            out[OFF_MIN + pix] = dep_sel - last_itv;
            out[OFF_MAX + pix] = dep_sel + last_itv;
        }
    }
    if (wv == 1 && wl < 3) {
        float v = npv.x*w_norm[wl*3+0] + npv.y*w_norm[wl*3+1] + npv.z*w_norm[wl*3+2];
        out[OFF_EST + wl*HWc + pix] = v;
    }
}

// ---------------- fallback path (original, untransposed) ----------------
__global__ void setup_kernel_fb(const float* __restrict__ rotation,
                                const float* __restrict__ proj,
                                float* __restrict__ wsf) {
    if (threadIdx.x != 0 || blockIdx.x != 0) return;
    unsigned int* wsu = (unsigned int*)wsf;
    wsu[0] = 0x7F800000u;
    wsu[1] = 0u;
    setup_body(rotation, proj, wsf);
}

__global__ __launch_bounds__(256)
void minmax_kernel_fb(const float* __restrict__ depth, unsigned int* __restrict__ wsu) {
    const int tid = blockIdx.x * blockDim.x + threadIdx.x;
    const int stride = gridDim.x * blockDim.x;
    const int n4 = (Dc*HWc) / 4;
    const float4* d4 = (const float4*)depth;
    float mn = __uint_as_float(0x7F800000u);
    float mx = 0.f;
    for (int idx = tid; idx < n4; idx += stride) {
        float4 v = d4[idx];
        mn = fminf(mn, fminf(fminf(v.x, v.y), fminf(v.z, v.w)));
        mx = fmaxf(mx, fmaxf(fmaxf(v.x, v.y), fmaxf(v.z, v.w)));
    }
    for (int off = 32; off; off >>= 1) {
        mn = fminf(mn, __shfl_xor(mn, off));
        mx = fmaxf(mx, __shfl_xor(mx, off));
    }
    __shared__ float smn[4], smx[4];
    const int w = threadIdx.x >> 6;
    if ((threadIdx.x & 63) == 0) { smn[w] = mn; smx[w] = mx; }
    __syncthreads();
    if (threadIdx.x == 0) {
        for (int i = 1; i < 4; i++) { mn = fminf(mn, smn[i]); mx = fmaxf(mx, smx[i]); }
        atomicMin(&wsu[0], __float_as_uint(mn));
        atomicMax(&wsu[1], __float_as_uint(mx));
    }
}

__global__ __launch_bounds__(256)
void main_kernel(const float* __restrict__ ref_feature,
                 const float* __restrict__ src_features,
                 const float* __restrict__ normal_plane,
                 const float* __restrict__ depth_hypo,
                 const float* __restrict__ w_reg,
                 const float* __restrict__ w_norm,
                 const float* __restrict__ wsf,
                 float* __restrict__ out) {
    const int pix = blockIdx.x;
    const int t = threadIdx.x;
    const int d = t & 31;
    const int g = t >> 5;
    const float fxp = (float)(pix % Wc);
    const float fyp = (float)(pix / Wc);

    __shared__ float s_cf[Gc*Dc];
    __shared__ float s_valid[Dc];

    float refv[4];
#pragma unroll
    for (int j = 0; j < 4; j++) refv[j] = ref_feature[(g*4+j)*HWc + pix];
    const float np0 = normal_plane[0*HWc + pix];
    const float np1 = normal_plane[1*HWc + pix];
    const float np2 = normal_plane[2*HWc + pix];
    const float depth_d = depth_hypo[d*HWc + pix];
    const float wreg_g = w_reg[g];

    float acc_cor = 0.f;
    float cws_acc = 1e-8f;
    float sumw_acc = 1e-8f;
    float nval_acc = 0.f;

    for (int i = 0; i < NSRC; i++) {
        const float* Wv = wsf + 2 + i*15;
        const float r00=Wv[0], r01=Wv[1], r02=Wv[2];
        const float r10=Wv[3], r11=Wv[4], r12=Wv[5];
        const float r20=Wv[6], r21=Wv[7], r22=Wv[8];
        const float t0=Wv[9], t1=Wv[10], t2=Wv[11];
        const float nv0=Wv[12], nv1=Wv[13], nv2=Wv[14];

        const float b0 = r00*fxp + r01*fyp + r02;
        const float b1 = r10*fxp + r11*fyp + r12;
        const float b2 = r20*fxp + r21*fyp + r22;

        float z = b2*depth_d + t2;
        if (z == 0.f) z = 1e-9f;
        const float px = (b0*depth_d + t0) / z;
        const float py = (b1*depth_d + t1) / z;

        const float fx0 = floorf(px), fy0 = floorf(py);
        const float wx = px - fx0, wy = py - fy0;
        const float fx1 = fx0 + 1.f, fy1 = fy0 + 1.f;
        const bool ix0 = (fx0 >= 0.f) && (fx0 <= (float)(Wc-1));
        const bool ix1 = (fx1 >= 0.f) && (fx1 <= (float)(Wc-1));
        const bool iy0 = (fy0 >= 0.f) && (fy0 <= (float)(Hc-1));
        const bool iy1 = (fy1 >= 0.f) && (fy1 <= (float)(Hc-1));
        const float w00 = (1.f-wx)*(1.f-wy) * ((ix0 && iy0) ? 1.f : 0.f);
        const float w10 = wx*(1.f-wy)       * ((ix1 && iy0) ? 1.f : 0.f);
        const float w01 = (1.f-wx)*wy       * ((ix0 && iy1) ? 1.f : 0.f);
        const float w11 = wx*wy             * ((ix1 && iy1) ? 1.f : 0.f);
        const int xi0 = (int)fminf(fmaxf(fx0, 0.f), (float)(Wc-1));
        const int xi1 = (int)fminf(fmaxf(fx1, 0.f), (float)(Wc-1));
        const int yi0 = (int)fminf(fmaxf(fy0, 0.f), (float)(Hc-1));
        const int yi1 = (int)fminf(fmaxf(fy1, 0.f), (float)(Hc-1));
        const int o00 = yi0*Wc + xi0, o10 = yi0*Wc + xi1;
        const int o01 = yi1*Wc + xi0, o11 = yi1*Wc + xi1;

        const float* src = src_features + (size_t)i * Cc * HWc;
        float corfeat = 0.f;
        float warp0 = 0.f;
#pragma unroll
        for (int j = 0; j < 4; j++) {
            const float* sc = src + (g*4 + j) * HWc;
            float v = w00*sc[o00] + w10*sc[o10] + w01*sc[o01] + w11*sc[o11];
            if (j == 0) warp0 = v;
            corfeat += v * refv[j];
        }
        corfeat *= 0.25f;

        s_cf[t] = corfeat;
        if (g == 0) s_valid[d] = (warp0 != 0.f) ? 1.f : 0.f;
        __syncthreads();

        float s_d = 0.f;
#pragma unroll
        for (int gg = 0; gg < Gc; gg++) s_d += s_cf[gg*32 + d];
        float m = s_d;
        for (int off = 1; off < 32; off <<= 1) m = fmaxf(m, __shfl_xor(m, off));
        float e = expf(s_d - m);
        float se = e;
        for (int off = 1; off < 32; off <<= 1) se += __shfl_xor(se, off);
        const float cor_w = (e / se) * 0.17677669529663687f;

        const float valid = s_valid[d];
        const float src_w = fmaxf(np0*nv0 + np1*nv1 + np2*nv2, 0.f) + 0.01f;
        const float sw = src_w * valid;

        acc_cor += cor_w * sw * corfeat;
        cws_acc += cor_w;
        sumw_acc += sw;
        nval_acc += valid;

        float ssum = sw;
        for (int off = 1; off < 32; off <<= 1) ssum += __shfl_xor(ssum, off);
        if (t == 0) out[OFF_WEIGHT + i*HWc + pix] = ssum * (1.f/32.f);
        __syncthreads();
    }

    const float cf_final = acc_cor / sumw_acc / cws_acc;
    s_cf[t] = cf_final * wreg_g;
    __syncthreads();
    float logit = 0.f;
#pragma unroll
    for (int gg = 0; gg < Gc; gg++) logit += s_cf[gg*32 + d];

    const unsigned int* wsu = (const unsigned int*)wsf;
    const float hmin = __uint_as_float(wsu[0]);
    const float hmax = __uint_as_float(wsu[1]);
    logit += (depth_d - hmin) / (hmax - hmin);

    float m = logit;
    for (int off = 1; off < 32; off <<= 1) m = fmaxf(m, __shfl_xor(m, off));
    float e = expf(logit - m);
    float se = e;
    for (int off = 1; off < 32; off <<= 1) se += __shfl_xor(se, off);
    const float attn = e / se;

    float av = attn; int ai = d;
    for (int off = 1; off < 32; off <<= 1) {
        float av2 = __shfl_xor(av, off);
        int ai2 = __shfl_xor(ai, off);
        if (av2 > av || (av2 == av && ai2 < ai)) { av = av2; ai = ai2; }
    }
    const float dep_sel = __shfl(depth_d, ai, 32);
    const float dep0 = __shfl(depth_d, 0, 32);
    const float dep1 = __shfl(depth_d, 1, 32);
    const float last_itv = dep1 - dep0;

    if (t < 32) {
        out[OFF_ATTN + d*HWc + pix] = attn;
        out[OFF_NVAL + d*HWc + pix] = nval_acc;
    }
    if (t == 0) {
        out[OFF_DEPTH + pix] = dep_sel;
        out[OFF_CONF + pix] = av;
        out[OFF_SW + pix] = sumw_acc * 0.25f;
        out[OFF_MIN + pix] = dep_sel - last_itv;
        out[OFF_MAX + pix] = dep_sel + last_itv;
    }
    if (t < 3) {
        float v = np0*w_norm[t*3+0] + np1*w_norm[t*3+1] + np2*w_norm[t*3+2];
        out[OFF_EST + t*HWc + pix] = v;
    }
}

extern "C" void kernel_launch(void* const* d_in, const int* in_sizes, int n_in,
                              void* d_out, int out_size, void* d_ws, size_t ws_size,
                              hipStream_t stream) {
    const float* ref   = (const float*)d_in[0];
    const float* src   = (const float*)d_in[1];
    const float* rot   = (const float*)d_in[2];
    const float* np_   = (const float*)d_in[3];
    const float* proj  = (const float*)d_in[4];
    const float* dh    = (const float*)d_in[5];
    const float* wreg  = (const float*)d_in[6];
    const float* wnorm = (const float*)d_in[7];
    float* out = (float*)d_out;
    float* ws  = (float*)d_ws;

    const size_t need_np   = (size_t)(NP_OFF + 4*HWc) * sizeof(float);
    const size_t need_base = (size_t)NP_OFF * sizeof(float);

    if (ws_size >= need_np) {
        dim3 tg(NTILE, 7);
        prep_kernel<<<tg, 256, 0, stream>>>(src, ref, dh, np_, rot, proj, ws);
        main_kernel_t<true><<<HWc, 128, 0, stream>>>(np_, wreg, wnorm, ws, out);
    } else if (ws_size >= need_base) {
        dim3 tg(NTILE, 6);
        prep_kernel<<<tg, 256, 0, stream>>>(src, ref, dh, np_, rot, proj, ws);
        main_kernel_t<false><<<HWc, 128, 0, stream>>>(np_, wreg, wnorm, ws, out);
    } else {
        hipMemsetAsync((char*)d_ws + 0, 0xFF, 4, stream);
        hipMemsetAsync((char*)d_ws + 4, 0x00, 4, stream);
        setup_kernel_fb<<<1, 1, 0, stream>>>(rot, proj, ws);
        minmax_kernel_fb<<<64, 256, 0, stream>>>(dh, (unsigned int*)ws);
        main_kernel<<<HWc, 256, 0, stream>>>(ref, src, np_, dh, wreg, wnorm, ws, out);
    }
}

// Round 9
// 150.793 us; speedup vs baseline: 1.2709x; 1.2709x over previous
//
#include <hip/hip_runtime.h>
#include <math.h>

#define Vc 5
#define Cc 32
#define Gc 8
#define Dc 32
#define Hc 192
#define Wc 192
#define HWc (Hc*Wc)
#define NSRC (Vc-1)
#define NTILE (HWc/64)   // 576

// output offsets (floats)
#define OFF_DEPTH  0
#define OFF_CONF   (HWc)
#define OFF_ATTN   (2*HWc)
#define OFF_EST    (OFF_ATTN + Dc*HWc)
#define OFF_SW     (OFF_EST + 3*HWc)
#define OFF_WEIGHT (OFF_SW + HWc)
#define OFF_NVAL   (OFF_WEIGHT + NSRC*HWc)
#define OFF_MIN    (OFF_NVAL + Dc*HWc)
#define OFF_MAX    (OFF_MIN + HWc)

// ws layout (floats):
//   [0]=hmin [1]=hmax (fallback path only)
//   [2 + i*15]: rot(9), trans(3), norv(3)
//   [T_OFF]: channels-last images, img=0..3 src, 4 ref, 5 depth ([HW][32] each)
//   [PART_OFF]: 576 partial (min,max) pairs from prep depth blocks
//   [NP_OFF]: normal_plane packed [HW][4]
#define T_OFF 64
#define PART_OFF (T_OFF + 6*Cc*HWc)
#define NP_OFF (PART_OFF + 2*NTILE)

__device__ void inv4(const float* A, float* out) {
    float M[4][8];
    for (int r = 0; r < 4; r++) {
        for (int c = 0; c < 4; c++) { M[r][c] = A[r*4+c]; M[r][c+4] = (r == c) ? 1.f : 0.f; }
    }
    for (int col = 0; col < 4; col++) {
        int piv = col; float best = fabsf(M[col][col]);
        for (int r = col+1; r < 4; r++) { float v = fabsf(M[r][col]); if (v > best) { best = v; piv = r; } }
        if (piv != col) for (int c = 0; c < 8; c++) { float t = M[col][c]; M[col][c] = M[piv][c]; M[piv][c] = t; }
        float inv = 1.f / M[col][col];
        for (int c = 0; c < 8; c++) M[col][c] *= inv;
        for (int r = 0; r < 4; r++) {
            if (r == col) continue;
            float f = M[r][col];
            for (int c = 0; c < 8; c++) M[r][c] -= f * M[col][c];
        }
    }
    for (int r = 0; r < 4; r++) for (int c = 0; c < 4; c++) out[r*4+c] = M[r][c+4];
}

__device__ void inv3(const float* A, float* out) {
    float a=A[0],b=A[1],c=A[2],d=A[3],e=A[4],f=A[5],g=A[6],h=A[7],i=A[8];
    float det = a*(e*i-f*h) - b*(d*i-f*g) + c*(d*h-e*g);
    float id = 1.f/det;
    out[0]=(e*i-f*h)*id; out[1]=(c*h-b*i)*id; out[2]=(b*f-c*e)*id;
    out[3]=(f*g-d*i)*id; out[4]=(a*i-c*g)*id; out[5]=(c*d-a*f)*id;
    out[6]=(d*h-e*g)*id; out[7]=(b*g-a*h)*id; out[8]=(a*e-b*d)*id;
}

__device__ void setup_body(const float* __restrict__ rotation,
                           const float* __restrict__ proj,
                           float* __restrict__ wsf) {
    float refE[16], refK[16], refNew[16], invRef[16];
    for (int k = 0; k < 16; k++) { refE[k] = proj[k]; refK[k] = proj[16+k]; }
    for (int k = 0; k < 16; k++) refNew[k] = refE[k];
    for (int r = 0; r < 3; r++) for (int c = 0; c < 4; c++) {
        float s = 0.f;
        for (int k = 0; k < 3; k++) s += refK[r*4+k] * refE[k*4+c];
        refNew[r*4+c] = s;
    }
    inv4(refNew, invRef);
    float invR0[9];
    inv3(rotation, invR0);

    for (int i = 0; i < NSRC; i++) {
        const float* E = proj + (i+1)*32;
        const float* K = proj + (i+1)*32 + 16;
        float sNew[16];
        for (int k = 0; k < 16; k++) sNew[k] = E[k];
        for (int r = 0; r < 3; r++) for (int c = 0; c < 4; c++) {
            float s = 0.f;
            for (int k = 0; k < 3; k++) s += K[r*4+k] * E[k*4+c];
            sNew[r*4+c] = s;
        }
        float P[16];
        for (int r = 0; r < 4; r++) for (int c = 0; c < 4; c++) {
            float s = 0.f;
            for (int k = 0; k < 4; k++) s += sNew[r*4+k] * invRef[k*4+c];
            P[r*4+c] = s;
        }
        float* o = wsf + 2 + i*15;
        for (int r = 0; r < 3; r++) for (int c = 0; c < 3; c++) o[r*3+c] = P[r*4+c];
        for (int r = 0; r < 3; r++) o[9+r] = P[r*4+3];
        const float* Ri = rotation + (i+1)*9;
        for (int c = 0; c < 3; c++) {
            float s = 0.f;
            for (int k = 0; k < 3; k++) s += Ri[2*3+k] * invR0[k*3+c];
            o[12+c] = s;
        }
    }
}

// Fused prep: transpose {src x4, ref, depth} to channels-last, depth partial
// min/max (plain stores), normal packed [HW][4], matrix setup on block (0,0).
__global__ __launch_bounds__(256)
void prep_kernel(const float* __restrict__ src,
                 const float* __restrict__ ref,
                 const float* __restrict__ depth,
                 const float* __restrict__ normal,
                 const float* __restrict__ rotation,
                 const float* __restrict__ proj,
                 float* __restrict__ wsf) {
    const int img = blockIdx.y;          // 0..6
    const int p0  = blockIdx.x * 64;
    const int t = threadIdx.x;

    if (img == 6) {  // normal_plane [3][HW] -> [HW][4]
        __shared__ float tl[3][64];
        if (t < 192) { const int c = t >> 6, p = t & 63; tl[c][p] = normal[c*HWc + p0 + p]; }
        __syncthreads();
        const int p = t >> 2, c = t & 3;
        wsf[NP_OFF + (size_t)(p0 + p)*4 + c] = (c < 3) ? tl[c][p] : 0.f;
        return;
    }

    const float* in = (img < NSRC) ? (src + (size_t)img*Cc*HWc)
                    : (img == NSRC) ? ref : depth;
    float* outp = wsf + T_OFF + (size_t)img * Cc * HWc;
    __shared__ float tile[Cc][64+1];
    float mn = __uint_as_float(0x7F800000u);
    float mx = 0.f;
#pragma unroll
    for (int k = 0; k < 8; k++) {
        const int c = (t >> 6) + k*4;
        const int p = t & 63;
        const float v = in[(size_t)c*HWc + p0 + p];
        tile[c][p] = v;
        mn = fminf(mn, v);
        mx = fmaxf(mx, v);
    }
    __syncthreads();
#pragma unroll
    for (int k = 0; k < 8; k++) {
        const int c = t & 31;
        const int p = (t >> 5) + k*8;
        outp[(size_t)(p0 + p)*Cc + c] = tile[c][p];
    }
    if (img == 5) {
        for (int off = 32; off; off >>= 1) {
            mn = fminf(mn, __shfl_xor(mn, off));
            mx = fmaxf(mx, __shfl_xor(mx, off));
        }
        __shared__ float smn[4], smx[4];
        const int w = t >> 6;
        if ((t & 63) == 0) { smn[w] = mn; smx[w] = mx; }
        __syncthreads();
        if (t == 0) {
            for (int i = 1; i < 4; i++) { mn = fminf(mn, smn[i]); mx = fmaxf(mx, smx[i]); }
            wsf[PART_OFF + blockIdx.x*2 + 0] = mn;
            wsf[PART_OFF + blockIdx.x*2 + 1] = mx;
        }
    }
    if (img == 0 && blockIdx.x == 0 && t == 0)
        setup_body(rotation, proj, wsf);
}

// Bilinear weight + BYTE tap-offset computation (uses Wv[0..11] only).
__device__ __forceinline__ void compute_wo(float fxp, float fyp, const float* __restrict__ Wv,
                                           float dep, float4* wout, int4* oout) {
    const float b0 = Wv[0]*fxp + Wv[1]*fyp + Wv[2];
    const float b1 = Wv[3]*fxp + Wv[4]*fyp + Wv[5];
    const float b2 = Wv[6]*fxp + Wv[7]*fyp + Wv[8];
    float z = fmaf(b2, dep, Wv[11]);
    if (z == 0.f) z = 1e-9f;
    float rz = __builtin_amdgcn_rcpf(z);
    rz = rz * (2.f - z * rz);                 // Newton refine
    const float px = fmaf(b0, dep, Wv[9])  * rz;
    const float py = fmaf(b1, dep, Wv[10]) * rz;

    const float fx0 = floorf(px), fy0 = floorf(py);
    const float wx = px - fx0, wy = py - fy0;
    const float fx1 = fx0 + 1.f, fy1 = fy0 + 1.f;
    const bool ix0 = (fx0 >= 0.f) && (fx0 <= (float)(Wc-1));
    const bool ix1 = (fx1 >= 0.f) && (fx1 <= (float)(Wc-1));
    const bool iy0 = (fy0 >= 0.f) && (fy0 <= (float)(Hc-1));
    const bool iy1 = (fy1 >= 0.f) && (fy1 <= (float)(Hc-1));
    const float w00 = (1.f-wx)*(1.f-wy) * ((ix0 && iy0) ? 1.f : 0.f);
    const float w10 = wx*(1.f-wy)       * ((ix1 && iy0) ? 1.f : 0.f);
    const float w01 = (1.f-wx)*wy       * ((ix0 && iy1) ? 1.f : 0.f);
    const float w11 = wx*wy             * ((ix1 && iy1) ? 1.f : 0.f);
    const int xi0 = (int)fminf(fmaxf(fx0, 0.f), (float)(Wc-1));
    const int xi1 = (int)fminf(fmaxf(fx1, 0.f), (float)(Wc-1));
    const int yi0 = (int)fminf(fmaxf(fy0, 0.f), (float)(Hc-1));
    const int yi1 = (int)fminf(fmaxf(fy1, 0.f), (float)(Hc-1));
    *wout = make_float4(w00, w10, w01, w11);
    *oout = make_int4((yi0*Wc + xi0) << 7, (yi0*Wc + xi1) << 7,
                      (yi1*Wc + xi0) << 7, (yi1*Wc + xi1) << 7);   // BYTES
}

// 128-thread, 1-pixel main kernel with uniform-cell fast path.
// Key identity: part(d) = sum_i cw*sw*wcf(d,i) / (sumw(d)*cws(d)) where
// wcf = sum_g wreg(g)*corfeat(g) — so per-(g,d) state is never needed
// downstream. When all 32 d's share the same 2x2 tap cells (ballot in
// phase 1), the blend commutes with the g-contraction: per view only
// S_tap = sum_g cell.rv, T_tap = sum_g wreg*cell.rv, c0_tap are needed
// (one dense 128-lane pass), and per-(view,d) work is 12 FMA.
template<bool USE_NPT>
__global__ __launch_bounds__(128, 8)
void main_kernel_t(const float* __restrict__ normal_plane,
                   const float* __restrict__ w_reg,
                   const float* __restrict__ w_norm,
                   const float* __restrict__ wsf,
                   float* __restrict__ out) {
    const int bid = blockIdx.x;
    const int pix = (bid & 7) * (HWc/8) + (bid >> 3);   // bijective XCD swizzle
    const int t = threadIdx.x;      // 0..127
    const int g = t & 7;
    const int dh = t >> 3;          // 0..15 (slow path: also dh+16)
    const int wv = t >> 6;          // wave 0/1
    const int wl = t & 63;
    const float fxp = (float)(pix % Wc);
    const float fyp = (float)(pix / Wc);

    const char*   srcB = (const char*)(wsf + T_OFF);
    const float4* refT = (const float4*)(wsf + T_OFF + (size_t)4*Cc*HWc);
    const float*  depT = wsf + T_OFF + (size_t)5*Cc*HWc;

    __shared__ float4 s_wt[NSRC][Dc];
    __shared__ int4   s_of[NSRC][Dc];
    __shared__ float  s_sd[NSRC][Dc];
    __shared__ float  s_wcf[NSRC][Dc];
    __shared__ float  s_val[NSRC][Dc];
    __shared__ float  s_w[NSRC][Dc];
    __shared__ float  s_sw[NSRC][Dc];
    __shared__ float  s_S[NSRC][4], s_T[NSRC][4], s_c0[NSRC][4];
    __shared__ int    s_uni[NSRC];
    __shared__ float  s_hmm[2];

    float4 rv = refT[pix*8 + g];
    rv.x *= 0.25f; rv.y *= 0.25f; rv.z *= 0.25f; rv.w *= 0.25f;
    float4 npv;
    if (USE_NPT) {
        npv = ((const float4*)(wsf + NP_OFF))[pix];
    } else {
        npv = make_float4(normal_plane[pix], normal_plane[HWc+pix],
                          normal_plane[2*HWc+pix], 0.f);
    }
    const float wreg_g = w_reg[g];

    // ---- phase 1 (dense): lane -> (view, d) weights + uniformity ballot ----
    {
        const int vvv = (wv << 1) | (wl >> 5);
        const int dd = wl & 31;
        const float* Wa = wsf + 2 + (wv << 1)*15;
        const float* Wb = Wa + 15;
        float Wv[12];
#pragma unroll
        for (int k = 0; k < 12; k++) Wv[k] = (wl < 32) ? Wa[k] : Wb[k];
        float4 wt; int4 of;
        compute_wo(fxp, fyp, Wv, depT[(size_t)pix*Dc + dd], &wt, &of);
        s_wt[vvv][dd] = wt;
        s_of[vvv][dd] = of;
        // are all 32 d's offsets identical? (half-wave ballot)
        const int base = wl & 32;
        const int o0x = __shfl(of.x, base), o0y = __shfl(of.y, base);
        const int o0z = __shfl(of.z, base), o0w = __shfl(of.w, base);
        const bool eq = (of.x == o0x) && (of.y == o0y) && (of.z == o0z) && (of.w == o0w);
        const unsigned long long b = __ballot(eq);
        if ((wl & 31) == 0)
            s_uni[vvv] = (((b >> base) & 0xFFFFFFFFull) == 0xFFFFFFFFull) ? 1 : 0;

        if (wv == 1) {   // reduce 576 partial (min,max) pairs
            float mn = __uint_as_float(0x7F800000u);
            float mx = 0.f;
#pragma unroll
            for (int j = 0; j < 9; j++) {
                mn = fminf(mn, wsf[PART_OFF + (wl + 64*j)*2 + 0]);
                mx = fmaxf(mx, wsf[PART_OFF + (wl + 64*j)*2 + 1]);
            }
            for (int off = 32; off; off >>= 1) {
                mn = fminf(mn, __shfl_xor(mn, off));
                mx = fmaxf(mx, __shfl_xor(mx, off));
            }
            if (wl == 0) { s_hmm[0] = mn; s_hmm[1] = mx; }
        }
    }
    __syncthreads();

    // ---- phase 2a: dense fast pass for uniform views ----
    // lane -> (view = t>>5, tap = (t>>3)&3, g = t&7); one gather + dot + reduce
    {
        const int v = t >> 5;
        if (s_uni[v]) {
            const int tap = (t >> 3) & 3;
            const int4 ov = s_of[v][0];
            const int o = (tap == 0) ? ov.x : (tap == 1) ? ov.y : (tap == 2) ? ov.z : ov.w;
            const char* sp = srcB + (size_t)v*(Cc*HWc*4);
            const float4 cell = *(const float4*)(sp + (unsigned)o + (unsigned)(g << 4));
            const float dot = cell.x*rv.x + cell.y*rv.y + cell.z*rv.z + cell.w*rv.w;
            float S = dot, T = dot * wreg_g;
            S += __shfl_xor(S, 1); S += __shfl_xor(S, 2); S += __shfl_xor(S, 4);
            T += __shfl_xor(T, 1); T += __shfl_xor(T, 2); T += __shfl_xor(T, 4);
            if (g == 0) { s_S[v][tap] = S; s_T[v][tap] = T; s_c0[v][tap] = cell.x; }
        }
    }
    // ---- phase 2b: slow path for non-uniform views (all threads, 2 d each) ----
    const unsigned gb = (unsigned)(g << 4);
#pragma unroll
    for (int i = 0; i < NSRC; i++) {
        if (!s_uni[i]) {
            const char* sp = srcB + (size_t)i*(Cc*HWc*4);
#pragma unroll
            for (int dx = 0; dx < 2; dx++) {
                const int d = dh + dx*16;
                const float4 w4 = s_wt[i][d];
                const int4   ov = s_of[i][d];
                const float4 v00 = *(const float4*)(sp + ((unsigned)ov.x + gb));
                const float4 v10 = *(const float4*)(sp + ((unsigned)ov.y + gb));
                const float4 v01 = *(const float4*)(sp + ((unsigned)ov.z + gb));
                const float4 v11 = *(const float4*)(sp + ((unsigned)ov.w + gb));
                const float bx = w4.x*v00.x + w4.y*v10.x + w4.z*v01.x + w4.w*v11.x;
                const float by = w4.x*v00.y + w4.y*v10.y + w4.z*v01.y + w4.w*v11.y;
                const float bz = w4.x*v00.z + w4.y*v10.z + w4.z*v01.z + w4.w*v11.z;
                const float bw = w4.x*v00.w + w4.y*v10.w + w4.z*v01.w + w4.w*v11.w;
                const float cf = bx*rv.x + by*rv.y + bz*rv.z + bw*rv.w;
                float sd = cf;
                sd += __shfl_xor(sd, 1); sd += __shfl_xor(sd, 2); sd += __shfl_xor(sd, 4);
                float tw = cf * wreg_g;
                tw += __shfl_xor(tw, 1); tw += __shfl_xor(tw, 2); tw += __shfl_xor(tw, 4);
                if (g == 0) {
                    s_sd[i][d] = sd; s_wcf[i][d] = tw;
                    s_val[i][d] = (bx != 0.f) ? 1.f : 0.f;
                }
            }
        }
    }
    __syncthreads();

    // ---- phase 3 (dense): lane -> (view, d): s_d/wcf/val + softmax + srcw ----
    {
        const int vvv = t >> 5;
        const int dd = t & 31;
        float u, valv;
        if (s_uni[vvv]) {
            const float4 w4 = s_wt[vvv][dd];
            u = w4.x*s_S[vvv][0] + w4.y*s_S[vvv][1] + w4.z*s_S[vvv][2] + w4.w*s_S[vvv][3];
            const float wcfv = w4.x*s_T[vvv][0] + w4.y*s_T[vvv][1] + w4.z*s_T[vvv][2] + w4.w*s_T[vvv][3];
            const float c0 = w4.x*s_c0[vvv][0] + w4.y*s_c0[vvv][1] + w4.z*s_c0[vvv][2] + w4.w*s_c0[vvv][3];
            valv = (c0 != 0.f) ? 1.f : 0.f;
            s_wcf[vvv][dd] = wcfv;
            s_val[vvv][dd] = valv;
        } else {
            u = s_sd[vvv][dd];
            valv = s_val[vvv][dd];
        }
        float m = u;
        for (int off = 1; off < 32; off <<= 1) m = fmaxf(m, __shfl_xor(m, off));
        const float e = __expf(u - m);
        float se = e;
        for (int off = 1; off < 32; off <<= 1) se += __shfl_xor(se, off);
        float rse = __builtin_amdgcn_rcpf(se);
        rse = rse * (2.f - se * rse);
        s_w[vvv][dd] = e * rse * 0.17677669529663687f;  // softmax / sqrt(C)

        const float* Na = wsf + 2 + (wv << 1)*15 + 12;
        const float* Nb = Na + 15;
        const float n0 = (wl < 32) ? Na[0] : Nb[0];
        const float n1 = (wl < 32) ? Na[1] : Nb[1];
        const float n2 = (wl < 32) ? Na[2] : Nb[2];
        const float srcw_v = fmaxf(npv.x*n0 + npv.y*n1 + npv.z*n2, 0.f) + 0.01f;
        const float swv = srcw_v * valv;
        s_sw[vvv][dd] = swv;
        float ss = swv;
        for (int off = 1; off < 32; off <<= 1) ss += __shfl_xor(ss, off);
        if ((wl & 31) == 0) out[OFF_WEIGHT + vvv*HWc + pix] = ss * (1.f/32.f);
    }
    __syncthreads();

    // ---- epilogue: wave0 (t<32 = d): per-d contraction + attn + outputs ----
    if (t < 32) {
        const int d = t;
        float num = 0.f, cws = 1e-8f, sumw = 1e-8f, nval = 0.f;
#pragma unroll
        for (int i = 0; i < NSRC; i++) {
            const float cw = s_w[i][d];
            const float sw = s_sw[i][d];
            num = fmaf(cw * sw, s_wcf[i][d], num);
            cws += cw; sumw += sw; nval += s_val[i][d];
        }
        float r1 = __builtin_amdgcn_rcpf(sumw);
        r1 = r1 * (2.f - sumw * r1);
        float r2 = __builtin_amdgcn_rcpf(cws);
        r2 = r2 * (2.f - cws * r2);
        const float part = num * r1 * r2;

        const float hmin = s_hmm[0];
        const float hr = s_hmm[1] - hmin;
        float rhr = __builtin_amdgcn_rcpf(hr);
        rhr = rhr * (2.f - hr * rhr);
        const float dep = depT[(size_t)pix*Dc + d];
        const float L = part + (dep - hmin) * rhr;

        float m = L;
        for (int off = 1; off < 32; off <<= 1) m = fmaxf(m, __shfl_xor(m, off));
        const float e = __expf(L - m);
        float se = e;
        for (int off = 1; off < 32; off <<= 1) se += __shfl_xor(se, off);
        float rse = __builtin_amdgcn_rcpf(se);
        rse = rse * (2.f - se * rse);
        const float attn = e * rse;

        out[OFF_ATTN + d*HWc + pix] = attn;
        out[OFF_NVAL + d*HWc + pix] = nval;

        float av = attn; int ai = d;
        for (int off = 1; off < 32; off <<= 1) {
            float av2 = __shfl_xor(av, off);
            int ai2 = __shfl_xor(ai, off);
            if (av2 > av || (av2 == av && ai2 < ai)) { av = av2; ai = ai2; }
        }
        const float dep_sel = __shfl(dep, ai);
        const float dep0 = __shfl(dep, 0);
        const float dep1 = __shfl(dep, 1);
        if (d == 0) {
            const float last_itv = dep1 - dep0;
            out[OFF_DEPTH + pix] = dep_sel;
            out[OFF_CONF + pix] = av;
            out[OFF_SW + pix] = sumw * 0.25f;   // d==0, /nsrc
            out[OFF_MIN + pix] = dep_sel - last_itv;
            out[OFF_MAX + pix] = dep_sel + last_itv;
        }
    }
    if (wv == 1 && wl < 3) {
        float v = npv.x*w_norm[wl*3+0] + npv.y*w_norm[wl*3+1] + npv.z*w_norm[wl*3+2];
        out[OFF_EST + wl*HWc + pix] = v;
    }
}

// ---------------- fallback path (original, untransposed) ----------------
__global__ void setup_kernel_fb(const float* __restrict__ rotation,
                                const float* __restrict__ proj,
                                float* __restrict__ wsf) {
    if (threadIdx.x != 0 || blockIdx.x != 0) return;
    unsigned int* wsu = (unsigned int*)wsf;
    wsu[0] = 0x7F800000u;
    wsu[1] = 0u;
    setup_body(rotation, proj, wsf);
}

__global__ __launch_bounds__(256)
void minmax_kernel_fb(const float* __restrict__ depth, unsigned int* __restrict__ wsu) {
    const int tid = blockIdx.x * blockDim.x + threadIdx.x;
    const int stride = gridDim.x * blockDim.x;
    const int n4 = (Dc*HWc) / 4;
    const float4* d4 = (const float4*)depth;
    float mn = __uint_as_float(0x7F800000u);
    float mx = 0.f;
    for (int idx = tid; idx < n4; idx += stride) {
        float4 v = d4[idx];
        mn = fminf(mn, fminf(fminf(v.x, v.y), fminf(v.z, v.w)));
        mx = fmaxf(mx, fmaxf(fmaxf(v.x, v.y), fmaxf(v.z, v.w)));
    }
    for (int off = 32; off; off >>= 1) {
        mn = fminf(mn, __shfl_xor(mn, off));
        mx = fmaxf(mx, __shfl_xor(mx, off));
    }
    __shared__ float smn[4], smx[4];
    const int w = threadIdx.x >> 6;
    if ((threadIdx.x & 63) == 0) { smn[w] = mn; smx[w] = mx; }
    __syncthreads();
    if (threadIdx.x == 0) {
        for (int i = 1; i < 4; i++) { mn = fminf(mn, smn[i]); mx = fmaxf(mx, smx[i]); }
        atomicMin(&wsu[0], __float_as_uint(mn));
        atomicMax(&wsu[1], __float_as_uint(mx));
    }
}

__global__ __launch_bounds__(256)
void main_kernel(const float* __restrict__ ref_feature,
                 const float* __restrict__ src_features,
                 const float* __restrict__ normal_plane,
                 const float* __restrict__ depth_hypo,
                 const float* __restrict__ w_reg,
                 const float* __restrict__ w_norm,
                 const float* __restrict__ wsf,
                 float* __restrict__ out) {
    const int pix = blockIdx.x;
    const int t = threadIdx.x;
    const int d = t & 31;
    const int g = t >> 5;
    const float fxp = (float)(pix % Wc);
    const float fyp = (float)(pix / Wc);

    __shared__ float s_cf[Gc*Dc];
    __shared__ float s_valid[Dc];

    float refv[4];
#pragma unroll
    for (int j = 0; j < 4; j++) refv[j] = ref_feature[(g*4+j)*HWc + pix];
    const float np0 = normal_plane[0*HWc + pix];
    const float np1 = normal_plane[1*HWc + pix];
    const float np2 = normal_plane[2*HWc + pix];
    const float depth_d = depth_hypo[d*HWc + pix];
    const float wreg_g = w_reg[g];

    float acc_cor = 0.f;
    float cws_acc = 1e-8f;
    float sumw_acc = 1e-8f;
    float nval_acc = 0.f;

    for (int i = 0; i < NSRC; i++) {
        const float* Wv = wsf + 2 + i*15;
        const float r00=Wv[0], r01=Wv[1], r02=Wv[2];
        const float r10=Wv[3], r11=Wv[4], r12=Wv[5];
        const float r20=Wv[6], r21=Wv[7], r22=Wv[8];
        const float t0=Wv[9], t1=Wv[10], t2=Wv[11];
        const float nv0=Wv[12], nv1=Wv[13], nv2=Wv[14];

        const float b0 = r00*fxp + r01*fyp + r02;
        const float b1 = r10*fxp + r11*fyp + r12;
        const float b2 = r20*fxp + r21*fyp + r22;

        float z = b2*depth_d + t2;
        if (z == 0.f) z = 1e-9f;
        const float px = (b0*depth_d + t0) / z;
        const float py = (b1*depth_d + t1) / z;

        const float fx0 = floorf(px), fy0 = floorf(py);
        const float wx = px - fx0, wy = py - fy0;
        const float fx1 = fx0 + 1.f, fy1 = fy0 + 1.f;
        const bool ix0 = (fx0 >= 0.f) && (fx0 <= (float)(Wc-1));
        const bool ix1 = (fx1 >= 0.f) && (fx1 <= (float)(Wc-1));
        const bool iy0 = (fy0 >= 0.f) && (fy0 <= (float)(Hc-1));
        const bool iy1 = (fy1 >= 0.f) && (fy1 <= (float)(Hc-1));
        const float w00 = (1.f-wx)*(1.f-wy) * ((ix0 && iy0) ? 1.f : 0.f);
        const float w10 = wx*(1.f-wy)       * ((ix1 && iy0) ? 1.f : 0.f);
        const float w01 = (1.f-wx)*wy       * ((ix0 && iy1) ? 1.f : 0.f);
        const float w11 = wx*wy             * ((ix1 && iy1) ? 1.f : 0.f);
        const int xi0 = (int)fminf(fmaxf(fx0, 0.f), (float)(Wc-1));
        const int xi1 = (int)fminf(fmaxf(fx1, 0.f), (float)(Wc-1));
        const int yi0 = (int)fminf(fmaxf(fy0, 0.f), (float)(Hc-1));
        const int yi1 = (int)fminf(fmaxf(fy1, 0.f), (float)(Hc-1));
        const int o00 = yi0*Wc + xi0, o10 = yi0*Wc + xi1;
        const int o01 = yi1*Wc + xi0, o11 = yi1*Wc + xi1;

        const float* src = src_features + (size_t)i * Cc * HWc;
        float corfeat = 0.f;
        float warp0 = 0.f;
#pragma unroll
        for (int j = 0; j < 4; j++) {
            const float* sc = src + (g*4 + j) * HWc;
            float v = w00*sc[o00] + w10*sc[o10] + w01*sc[o01] + w11*sc[o11];
            if (j == 0) warp0 = v;
            corfeat += v * refv[j];
        }
        corfeat *= 0.25f;

        s_cf[t] = corfeat;
        if (g == 0) s_valid[d] = (warp0 != 0.f) ? 1.f : 0.f;
        __syncthreads();

        float s_d = 0.f;
#pragma unroll
        for (int gg = 0; gg < Gc; gg++) s_d += s_cf[gg*32 + d];
        float m = s_d;
        for (int off = 1; off < 32; off <<= 1) m = fmaxf(m, __shfl_xor(m, off));
        float e = expf(s_d - m);
        float se = e;
        for (int off = 1; off < 32; off <<= 1) se += __shfl_xor(se, off);
        const float cor_w = (e / se) * 0.17677669529663687f;

        const float valid = s_valid[d];
        const float src_w = fmaxf(np0*nv0 + np1*nv1 + np2*nv2, 0.f) + 0.01f;
        const float sw = src_w * valid;

        acc_cor += cor_w * sw * corfeat;
        cws_acc += cor_w;
        sumw_acc += sw;
        nval_acc += valid;

        float ssum = sw;
        for (int off = 1; off < 32; off <<= 1) ssum += __shfl_xor(ssum, off);
        if (t == 0) out[OFF_WEIGHT + i*HWc + pix] = ssum * (1.f/32.f);
        __syncthreads();
    }

    const float cf_final = acc_cor / sumw_acc / cws_acc;
    s_cf[t] = cf_final * wreg_g;
    __syncthreads();
    float logit = 0.f;
#pragma unroll
    for (int gg = 0; gg < Gc; gg++) logit += s_cf[gg*32 + d];

    const unsigned int* wsu = (const unsigned int*)wsf;
    const float hmin = __uint_as_float(wsu[0]);
    const float hmax = __uint_as_float(wsu[1]);
    logit += (depth_d - hmin) / (hmax - hmin);

    float m = logit;
    for (int off = 1; off < 32; off <<= 1) m = fmaxf(m, __shfl_xor(m, off));
    float e = expf(logit - m);
    float se = e;
    for (int off = 1; off < 32; off <<= 1) se += __shfl_xor(se, off);
    const float attn = e / se;

    float av = attn; int ai = d;
    for (int off = 1; off < 32; off <<= 1) {
        float av2 = __shfl_xor(av, off);
        int ai2 = __shfl_xor(ai, off);
        if (av2 > av || (av2 == av && ai2 < ai)) { av = av2; ai = ai2; }
    }
    const float dep_sel = __shfl(depth_d, ai, 32);
    const float dep0 = __shfl(depth_d, 0, 32);
    const float dep1 = __shfl(depth_d, 1, 32);
    const float last_itv = dep1 - dep0;

    if (t < 32) {
        out[OFF_ATTN + d*HWc + pix] = attn;
        out[OFF_NVAL + d*HWc + pix] = nval_acc;
    }
    if (t == 0) {
        out[OFF_DEPTH + pix] = dep_sel;
        out[OFF_CONF + pix] = av;
        out[OFF_SW + pix] = sumw_acc * 0.25f;
        out[OFF_MIN + pix] = dep_sel - last_itv;
        out[OFF_MAX + pix] = dep_sel + last_itv;
    }
    if (t < 3) {
        float v = np0*w_norm[t*3+0] + np1*w_norm[t*3+1] + np2*w_norm[t*3+2];
        out[OFF_EST + t*HWc + pix] = v;
    }
}

extern "C" void kernel_launch(void* const* d_in, const int* in_sizes, int n_in,
                              void* d_out, int out_size, void* d_ws, size_t ws_size,
                              hipStream_t stream) {
    const float* ref   = (const float*)d_in[0];
    const float* src   = (const float*)d_in[1];
    const float* rot   = (const float*)d_in[2];
    const float* np_   = (const float*)d_in[3];
    const float* proj  = (const float*)d_in[4];
    const float* dh    = (const float*)d_in[5];
    const float* wreg  = (const float*)d_in[6];
    const float* wnorm = (const float*)d_in[7];
    float* out = (float*)d_out;
    float* ws  = (float*)d_ws;

    const size_t need_np   = (size_t)(NP_OFF + 4*HWc) * sizeof(float);
    const size_t need_base = (size_t)NP_OFF * sizeof(float);

    if (ws_size >= need_np) {
        dim3 tg(NTILE, 7);
        prep_kernel<<<tg, 256, 0, stream>>>(src, ref, dh, np_, rot, proj, ws);
        main_kernel_t<true><<<HWc, 128, 0, stream>>>(np_, wreg, wnorm, ws, out);
    } else if (ws_size >= need_base) {
        dim3 tg(NTILE, 6);
        prep_kernel<<<tg, 256, 0, stream>>>(src, ref, dh, np_, rot, proj, ws);
        main_kernel_t<false><<<HWc, 128, 0, stream>>>(np_, wreg, wnorm, ws, out);
    } else {
        hipMemsetAsync((char*)d_ws + 0, 0xFF, 4, stream);
        hipMemsetAsync((char*)d_ws + 4, 0x00, 4, stream);
        setup_kernel_fb<<<1, 1, 0, stream>>>(rot, proj, ws);
        minmax_kernel_fb<<<64, 256, 0, stream>>>(dh, (unsigned int*)ws);
        main_kernel<<<HWc, 256, 0, stream>>>(ref, src, np_, dh, wreg, wnorm, ws, out);
    }
}

// Round 10
// 149.650 us; speedup vs baseline: 1.2806x; 1.0076x over previous
//
#include <hip/hip_runtime.h>
#include <math.h>

#define Vc 5
#define Cc 32
#define Gc 8
#define Dc 32
#define Hc 192
#define Wc 192
#define HWc (Hc*Wc)
#define NSRC (Vc-1)
#define NTILE (HWc/64)   // 576

// output offsets (floats)
#define OFF_DEPTH  0
#define OFF_CONF   (HWc)
#define OFF_ATTN   (2*HWc)
#define OFF_EST    (OFF_ATTN + Dc*HWc)
#define OFF_SW     (OFF_EST + 3*HWc)
#define OFF_WEIGHT (OFF_SW + HWc)
#define OFF_NVAL   (OFF_WEIGHT + NSRC*HWc)
#define OFF_MIN    (OFF_NVAL + Dc*HWc)
#define OFF_MAX    (OFF_MIN + HWc)

// ws layout (floats):
//   [0]=hmin [1]=hmax  (floats via reduce_kernel; fallback uses uint bits)
//   [2 + i*15]: rot(9), trans(3), norv(3)
//   [T_OFF]: channels-last images, img=0..3 src, 4 ref, 5 depth ([HW][32] each)
//   [PART_OFF]: 576 partial (min,max) pairs from prep depth blocks
//   [NP_OFF]: normal_plane packed [HW][4]
#define T_OFF 64
#define PART_OFF (T_OFF + 6*Cc*HWc)
#define NP_OFF (PART_OFF + 2*NTILE)

__device__ void inv4(const float* A, float* out) {
    float M[4][8];
    for (int r = 0; r < 4; r++) {
        for (int c = 0; c < 4; c++) { M[r][c] = A[r*4+c]; M[r][c+4] = (r == c) ? 1.f : 0.f; }
    }
    for (int col = 0; col < 4; col++) {
        int piv = col; float best = fabsf(M[col][col]);
        for (int r = col+1; r < 4; r++) { float v = fabsf(M[r][col]); if (v > best) { best = v; piv = r; } }
        if (piv != col) for (int c = 0; c < 8; c++) { float t = M[col][c]; M[col][c] = M[piv][c]; M[piv][c] = t; }
        float inv = 1.f / M[col][col];
        for (int c = 0; c < 8; c++) M[col][c] *= inv;
        for (int r = 0; r < 4; r++) {
            if (r == col) continue;
            float f = M[r][col];
            for (int c = 0; c < 8; c++) M[r][c] -= f * M[col][c];
        }
    }
    for (int r = 0; r < 4; r++) for (int c = 0; c < 4; c++) out[r*4+c] = M[r][c+4];
}

__device__ void inv3(const float* A, float* out) {
    float a=A[0],b=A[1],c=A[2],d=A[3],e=A[4],f=A[5],g=A[6],h=A[7],i=A[8];
    float det = a*(e*i-f*h) - b*(d*i-f*g) + c*(d*h-e*g);
    float id = 1.f/det;
    out[0]=(e*i-f*h)*id; out[1]=(c*h-b*i)*id; out[2]=(b*f-c*e)*id;
    out[3]=(f*g-d*i)*id; out[4]=(a*i-c*g)*id; out[5]=(c*d-a*f)*id;
    out[6]=(d*h-e*g)*id; out[7]=(b*g-a*h)*id; out[8]=(a*e-b*d)*id;
}

__device__ void setup_body(const float* __restrict__ rotation,
                           const float* __restrict__ proj,
                           float* __restrict__ wsf) {
    float refE[16], refK[16], refNew[16], invRef[16];
    for (int k = 0; k < 16; k++) { refE[k] = proj[k]; refK[k] = proj[16+k]; }
    for (int k = 0; k < 16; k++) refNew[k] = refE[k];
    for (int r = 0; r < 3; r++) for (int c = 0; c < 4; c++) {
        float s = 0.f;
        for (int k = 0; k < 3; k++) s += refK[r*4+k] * refE[k*4+c];
        refNew[r*4+c] = s;
    }
    inv4(refNew, invRef);
    float invR0[9];
    inv3(rotation, invR0);

    for (int i = 0; i < NSRC; i++) {
        const float* E = proj + (i+1)*32;
        const float* K = proj + (i+1)*32 + 16;
        float sNew[16];
        for (int k = 0; k < 16; k++) sNew[k] = E[k];
        for (int r = 0; r < 3; r++) for (int c = 0; c < 4; c++) {
            float s = 0.f;
            for (int k = 0; k < 3; k++) s += K[r*4+k] * E[k*4+c];
            sNew[r*4+c] = s;
        }
        float P[16];
        for (int r = 0; r < 4; r++) for (int c = 0; c < 4; c++) {
            float s = 0.f;
            for (int k = 0; k < 4; k++) s += sNew[r*4+k] * invRef[k*4+c];
            P[r*4+c] = s;
        }
        float* o = wsf + 2 + i*15;
        for (int r = 0; r < 3; r++) for (int c = 0; c < 3; c++) o[r*3+c] = P[r*4+c];
        for (int r = 0; r < 3; r++) o[9+r] = P[r*4+3];
        const float* Ri = rotation + (i+1)*9;
        for (int c = 0; c < 3; c++) {
            float s = 0.f;
            for (int k = 0; k < 3; k++) s += Ri[2*3+k] * invR0[k*3+c];
            o[12+c] = s;
        }
    }
}

// Fused prep: transpose {src x4, ref, depth} to channels-last, depth partial
// min/max (plain stores), normal packed [HW][4], matrix setup on block (0,0).
__global__ __launch_bounds__(256)
void prep_kernel(const float* __restrict__ src,
                 const float* __restrict__ ref,
                 const float* __restrict__ depth,
                 const float* __restrict__ normal,
                 const float* __restrict__ rotation,
                 const float* __restrict__ proj,
                 float* __restrict__ wsf) {
    const int img = blockIdx.y;          // 0..6
    const int p0  = blockIdx.x * 64;
    const int t = threadIdx.x;

    if (img == 6) {  // normal_plane [3][HW] -> [HW][4]
        __shared__ float tl[3][64];
        if (t < 192) { const int c = t >> 6, p = t & 63; tl[c][p] = normal[c*HWc + p0 + p]; }
        __syncthreads();
        const int p = t >> 2, c = t & 3;
        wsf[NP_OFF + (size_t)(p0 + p)*4 + c] = (c < 3) ? tl[c][p] : 0.f;
        return;
    }

    const float* in = (img < NSRC) ? (src + (size_t)img*Cc*HWc)
                    : (img == NSRC) ? ref : depth;
    float* outp = wsf + T_OFF + (size_t)img * Cc * HWc;
    __shared__ float tile[Cc][64+1];
    float mn = __uint_as_float(0x7F800000u);
    float mx = 0.f;
#pragma unroll
    for (int k = 0; k < 8; k++) {
        const int c = (t >> 6) + k*4;
        const int p = t & 63;
        const float v = in[(size_t)c*HWc + p0 + p];
        tile[c][p] = v;
        mn = fminf(mn, v);
        mx = fmaxf(mx, v);
    }
    __syncthreads();
#pragma unroll
    for (int k = 0; k < 8; k++) {
        const int c = t & 31;
        const int p = (t >> 5) + k*8;
        outp[(size_t)(p0 + p)*Cc + c] = tile[c][p];
    }
    if (img == 5) {
        for (int off = 32; off; off >>= 1) {
            mn = fminf(mn, __shfl_xor(mn, off));
            mx = fmaxf(mx, __shfl_xor(mx, off));
        }
        __shared__ float smn[4], smx[4];
        const int w = t >> 6;
        if ((t & 63) == 0) { smn[w] = mn; smx[w] = mx; }
        __syncthreads();
        if (t == 0) {
            for (int i = 1; i < 4; i++) { mn = fminf(mn, smn[i]); mx = fmaxf(mx, smx[i]); }
            wsf[PART_OFF + blockIdx.x*2 + 0] = mn;
            wsf[PART_OFF + blockIdx.x*2 + 1] = mx;
        }
    }
    if (img == 0 && blockIdx.x == 0 && t == 0)
        setup_body(rotation, proj, wsf);
}

// 1-block finalize: reduce 576 partial pairs -> ws[0]=hmin, ws[1]=hmax (floats).
__global__ __launch_bounds__(256)
void reduce_kernel(float* __restrict__ wsf) {
    const int t = threadIdx.x;
    float mn = __uint_as_float(0x7F800000u);
    float mx = 0.f;
    for (int idx = t; idx < NTILE; idx += 256) {
        mn = fminf(mn, wsf[PART_OFF + idx*2 + 0]);
        mx = fmaxf(mx, wsf[PART_OFF + idx*2 + 1]);
    }
    for (int off = 32; off; off >>= 1) {
        mn = fminf(mn, __shfl_xor(mn, off));
        mx = fmaxf(mx, __shfl_xor(mx, off));
    }
    __shared__ float smn[4], smx[4];
    const int w = t >> 6;
    if ((t & 63) == 0) { smn[w] = mn; smx[w] = mx; }
    __syncthreads();
    if (t == 0) {
        for (int i = 1; i < 4; i++) { mn = fminf(mn, smn[i]); mx = fmaxf(mx, smx[i]); }
        wsf[0] = mn;
        wsf[1] = mx;
    }
}

// Bilinear weight + BYTE tap-offset computation (uses Wv[0..11] only).
__device__ __forceinline__ void compute_wo(float fxp, float fyp, const float* __restrict__ Wv,
                                           float dep, float4* wout, int4* oout) {
    const float b0 = Wv[0]*fxp + Wv[1]*fyp + Wv[2];
    const float b1 = Wv[3]*fxp + Wv[4]*fyp + Wv[5];
    const float b2 = Wv[6]*fxp + Wv[7]*fyp + Wv[8];
    float z = fmaf(b2, dep, Wv[11]);
    if (z == 0.f) z = 1e-9f;
    float rz = __builtin_amdgcn_rcpf(z);
    rz = rz * (2.f - z * rz);                 // Newton refine
    const float px = fmaf(b0, dep, Wv[9])  * rz;
    const float py = fmaf(b1, dep, Wv[10]) * rz;

    const float fx0 = floorf(px), fy0 = floorf(py);
    const float wx = px - fx0, wy = py - fy0;
    const float fx1 = fx0 + 1.f, fy1 = fy0 + 1.f;
    const bool ix0 = (fx0 >= 0.f) && (fx0 <= (float)(Wc-1));
    const bool ix1 = (fx1 >= 0.f) && (fx1 <= (float)(Wc-1));
    const bool iy0 = (fy0 >= 0.f) && (fy0 <= (float)(Hc-1));
    const bool iy1 = (fy1 >= 0.f) && (fy1 <= (float)(Hc-1));
    const float w00 = (1.f-wx)*(1.f-wy) * ((ix0 && iy0) ? 1.f : 0.f);
    const float w10 = wx*(1.f-wy)       * ((ix1 && iy0) ? 1.f : 0.f);
    const float w01 = (1.f-wx)*wy       * ((ix0 && iy1) ? 1.f : 0.f);
    const float w11 = wx*wy             * ((ix1 && iy1) ? 1.f : 0.f);
    const int xi0 = (int)fminf(fmaxf(fx0, 0.f), (float)(Wc-1));
    const int xi1 = (int)fminf(fmaxf(fx1, 0.f), (float)(Wc-1));
    const int yi0 = (int)fminf(fmaxf(fy0, 0.f), (float)(Hc-1));
    const int yi1 = (int)fminf(fmaxf(fy1, 0.f), (float)(Hc-1));
    *wout = make_float4(w00, w10, w01, w11);
    *oout = make_int4((yi0*Wc + xi0) << 7, (yi0*Wc + xi1) << 7,
                      (yi1*Wc + xi0) << 7, (yi1*Wc + xi1) << 7);   // BYTES
}

// Wave-per-pixel main kernel: 256 threads = 4 independent 64-lane waves,
// each wave owns one pixel, ZERO __syncthreads. Per lane, 2 register items
// k=0,1: (v = 2k + (wl>>5), d = wl&31). All cross-lane traffic is wave-
// internal shuffles; the rare non-uniform path uses a small per-wave LDS
// buffer (same-wave DS ops are in-order; asm lgkmcnt + memory clobber
// orders compiler). hmin/hmax come precomputed from reduce_kernel.
template<bool USE_NPT>
__global__ __launch_bounds__(256, 4)
void main_kernel_t(const float* __restrict__ normal_plane,
                   const float* __restrict__ w_reg,
                   const float* __restrict__ w_norm,
                   const float* __restrict__ wsf,
                   float* __restrict__ out) {
    const int bid = blockIdx.x;
    const int wq = threadIdx.x >> 6;    // wave id 0..3 (one pixel each)
    const int wl = threadIdx.x & 63;
    const int grp = (bid & 7) * (HWc/32) + (bid >> 3);   // bijective XCD swizzle
    const int pix = grp*4 + wq;
    const int g = wl & 7;
    const float fxp = (float)(pix % Wc);
    const float fyp = (float)(pix / Wc);

    const char*   srcB = (const char*)(wsf + T_OFF);
    const float4* refT = (const float4*)(wsf + T_OFF + (size_t)4*Cc*HWc);
    const float*  depT = wsf + T_OFF + (size_t)5*Cc*HWc;

    // slow-path-only LDS (per wave region), no barriers needed (same wave)
    __shared__ float s_sd[4][NSRC][Dc];
    __shared__ float s_tw[4][NSRC][Dc];
    __shared__ float s_val[4][NSRC][Dc];

    float4 rv = refT[pix*8 + g];
    rv.x *= 0.25f; rv.y *= 0.25f; rv.z *= 0.25f; rv.w *= 0.25f;
    float4 npv;
    if (USE_NPT) {
        npv = ((const float4*)(wsf + NP_OFF))[pix];
    } else {
        npv = make_float4(normal_plane[pix], normal_plane[HWc+pix],
                          normal_plane[2*HWc+pix], 0.f);
    }
    const float wreg_g = w_reg[g];
    const float dep_d = depT[(size_t)pix*Dc + (wl & 31)];
    const float hmin = wsf[0];
    const float hmax = wsf[1];

    // ---- phase 1: 2 x compute_wo per lane (items (v,d)) + uniformity ----
    float4 wt0, wt1; int4 of0, of1;
    {
        const float* A0 = wsf + 2 + 0*15;
        const float* B0 = A0 + 15;
        float Wv[12];
#pragma unroll
        for (int j = 0; j < 12; j++) Wv[j] = (wl < 32) ? A0[j] : B0[j];
        compute_wo(fxp, fyp, Wv, dep_d, &wt0, &of0);
        const float* A1 = wsf + 2 + 2*15;
        const float* B1 = A1 + 15;
#pragma unroll
        for (int j = 0; j < 12; j++) Wv[j] = (wl < 32) ? A1[j] : B1[j];
        compute_wo(fxp, fyp, Wv, dep_d, &wt1, &of1);
    }
    bool u0, u1, u2, u3;
    {
        const int bl = wl & 32;
        int rx = __shfl(of0.x, bl), ry = __shfl(of0.y, bl);
        int rz = __shfl(of0.z, bl), rw = __shfl(of0.w, bl);
        const bool e0 = (of0.x==rx) && (of0.y==ry) && (of0.z==rz) && (of0.w==rw);
        const unsigned long long b0 = __ballot(e0);
        u0 = (b0 & 0xFFFFFFFFull) == 0xFFFFFFFFull;
        u1 = (b0 >> 32) == 0xFFFFFFFFull;
        rx = __shfl(of1.x, bl); ry = __shfl(of1.y, bl);
        rz = __shfl(of1.z, bl); rw = __shfl(of1.w, bl);
        const bool e1 = (of1.x==rx) && (of1.y==ry) && (of1.z==rz) && (of1.w==rw);
        const unsigned long long b1 = __ballot(e1);
        u2 = (b1 & 0xFFFFFFFFull) == 0xFFFFFFFFull;
        u3 = (b1 >> 32) == 0xFFFFFFFFull;
    }

    // ---- phase 2 fast: for uniform views, lane -> (v, tap, g) ----
    // own of/wt ARE the shared cell (all d identical). 1 gather + dot + 8-reduce.
    const int tap = (wl >> 3) & 3;
    float S0 = 0.f, T0 = 0.f, C0 = 0.f;   // k=0 (view = wl>>5)
    float S1 = 0.f, T1 = 0.f, C1 = 0.f;   // k=1 (view = 2 + (wl>>5))
    {
        const bool uva = (wl & 32) ? u1 : u0;
        if (uva) {
            const int v = (wl >> 5);
            const int o = (tap == 0) ? of0.x : (tap == 1) ? of0.y : (tap == 2) ? of0.z : of0.w;
            const char* sp = srcB + (size_t)v*(Cc*HWc*4);
            const float4 cell = *(const float4*)(sp + (unsigned)o + (unsigned)(g << 4));
            const float dot = cell.x*rv.x + cell.y*rv.y + cell.z*rv.z + cell.w*rv.w;
            float S = dot, T = dot * wreg_g;
            S += __shfl_xor(S, 1); S += __shfl_xor(S, 2); S += __shfl_xor(S, 4);
            T += __shfl_xor(T, 1); T += __shfl_xor(T, 2); T += __shfl_xor(T, 4);
            S0 = S; T0 = T; C0 = __shfl(cell.x, wl & ~7);
        }
        const bool uvb = (wl & 32) ? u3 : u2;
        if (uvb) {
            const int v = 2 + (wl >> 5);
            const int o = (tap == 0) ? of1.x : (tap == 1) ? of1.y : (tap == 2) ? of1.z : of1.w;
            const char* sp = srcB + (size_t)v*(Cc*HWc*4);
            const float4 cell = *(const float4*)(sp + (unsigned)o + (unsigned)(g << 4));
            const float dot = cell.x*rv.x + cell.y*rv.y + cell.z*rv.z + cell.w*rv.w;
            float S = dot, T = dot * wreg_g;
            S += __shfl_xor(S, 1); S += __shfl_xor(S, 2); S += __shfl_xor(S, 4);
            T += __shfl_xor(T, 1); T += __shfl_xor(T, 2); T += __shfl_xor(T, 4);
            S1 = S; T1 = T; C1 = __shfl(cell.x, wl & ~7);
        }
    }

    // ---- phase 2 slow: non-uniform views, lane -> (g, d4), 4 d's each ----
    if (!(u0 && u1 && u2 && u3)) {
        const int d4 = wl >> 3;          // 0..7
#pragma unroll
        for (int i = 0; i < NSRC; i++) {
            const bool ui = (i == 0) ? u0 : (i == 1) ? u1 : (i == 2) ? u2 : u3;
            if (!ui) {
                const char* sp = srcB + (size_t)i*(Cc*HWc*4);
#pragma unroll
                for (int j = 0; j < 4; j++) {
                    const int dd = d4 + 8*j;
                    const int lp = ((i & 1) << 5) | dd;   // producer lane of (i,dd)
                    float4 w4; int4 ov;
                    if (i < 2) {
                        w4.x = __shfl(wt0.x, lp); w4.y = __shfl(wt0.y, lp);
                        w4.z = __shfl(wt0.z, lp); w4.w = __shfl(wt0.w, lp);
                        ov.x = __shfl(of0.x, lp); ov.y = __shfl(of0.y, lp);
                        ov.z = __shfl(of0.z, lp); ov.w = __shfl(of0.w, lp);
                    } else {
                        w4.x = __shfl(wt1.x, lp); w4.y = __shfl(wt1.y, lp);
                        w4.z = __shfl(wt1.z, lp); w4.w = __shfl(wt1.w, lp);
                        ov.x = __shfl(of1.x, lp); ov.y = __shfl(of1.y, lp);
                        ov.z = __shfl(of1.z, lp); ov.w = __shfl(of1.w, lp);
                    }
                    const float4 v00 = *(const float4*)(sp + ((unsigned)ov.x + (unsigned)(g<<4)));
                    const float4 v10 = *(const float4*)(sp + ((unsigned)ov.y + (unsigned)(g<<4)));
                    const float4 v01 = *(const float4*)(sp + ((unsigned)ov.z + (unsigned)(g<<4)));
                    const float4 v11 = *(const float4*)(sp + ((unsigned)ov.w + (unsigned)(g<<4)));
                    const float bx = w4.x*v00.x + w4.y*v10.x + w4.z*v01.x + w4.w*v11.x;
                    const float by = w4.x*v00.y + w4.y*v10.y + w4.z*v01.y + w4.w*v11.y;
                    const float bz = w4.x*v00.z + w4.y*v10.z + w4.z*v01.z + w4.w*v11.z;
                    const float bw = w4.x*v00.w + w4.y*v10.w + w4.z*v01.w + w4.w*v11.w;
                    const float cf = bx*rv.x + by*rv.y + bz*rv.z + bw*rv.w;
                    float sd = cf;
                    sd += __shfl_xor(sd, 1); sd += __shfl_xor(sd, 2); sd += __shfl_xor(sd, 4);
                    float tw = cf * wreg_g;
                    tw += __shfl_xor(tw, 1); tw += __shfl_xor(tw, 2); tw += __shfl_xor(tw, 4);
                    if (g == 0) {
                        s_sd[wq][i][dd] = sd;
                        s_tw[wq][i][dd] = tw;
                        s_val[wq][i][dd] = (bx != 0.f) ? 1.f : 0.f;
                    }
                }
            }
        }
        asm volatile("s_waitcnt lgkmcnt(0)" ::: "memory");
    }

    // ---- phase 3: per k, (v,d) softmax over d + srcw + sims ----
    float w_k[2], sw_k[2], wcf_k[2], val_k[2];
#pragma unroll
    for (int k = 0; k < 2; k++) {
        const int v = 2*k + (wl >> 5);
        const float4 wt = k ? wt1 : wt0;
        const bool uv = (wl & 32) ? (k ? u3 : u1) : (k ? u2 : u0);
        float u, wcf, valv;
        if (uv) {
            float c0s = 0.f;
            u = 0.f; wcf = 0.f;
#pragma unroll
            for (int tp = 0; tp < 4; tp++) {
                const int lanep = (wl & 32) | (tp << 3);
                const float Sp = __shfl(k ? S1 : S0, lanep);
                const float Tp = __shfl(k ? T1 : T0, lanep);
                const float Cp = __shfl(k ? C1 : C0, lanep);
                const float wc = (tp == 0) ? wt.x : (tp == 1) ? wt.y : (tp == 2) ? wt.z : wt.w;
                u   = fmaf(wc, Sp, u);
                wcf = fmaf(wc, Tp, wcf);
                c0s = fmaf(wc, Cp, c0s);
            }
            valv = (c0s != 0.f) ? 1.f : 0.f;
        } else {
            const int dd = wl & 31;
            u    = s_sd[wq][v][dd];
            wcf  = s_tw[wq][v][dd];
            valv = s_val[wq][v][dd];
        }
        // softmax over d within the 32-lane half
        float m = u;
        for (int off = 1; off < 32; off <<= 1) m = fmaxf(m, __shfl_xor(m, off));
        const float e = __expf(u - m);
        float se = e;
        for (int off = 1; off < 32; off <<= 1) se += __shfl_xor(se, off);
        float rse = __builtin_amdgcn_rcpf(se);
        rse = rse * (2.f - se * rse);
        w_k[k] = e * rse * 0.17677669529663687f;   // softmax / sqrt(C)

        const float* Na = wsf + 2 + (2*k)*15 + 12;
        const float* Nb = Na + 15;
        const float n0 = (wl < 32) ? Na[0] : Nb[0];
        const float n1 = (wl < 32) ? Na[1] : Nb[1];
        const float n2 = (wl < 32) ? Na[2] : Nb[2];
        const float srcw_v = fmaxf(npv.x*n0 + npv.y*n1 + npv.z*n2, 0.f) + 0.01f;
        sw_k[k] = srcw_v * valv;
        wcf_k[k] = wcf;
        val_k[k] = valv;

        float ss = sw_k[k];
        for (int off = 1; off < 32; off <<= 1) ss += __shfl_xor(ss, off);
        if ((wl & 31) == 0) out[OFF_WEIGHT + v*HWc + pix] = ss * (1.f/32.f);
    }

    // ---- phase 4: per-d contraction over the 4 views (register + 1 xor32) ----
    float num = w_k[0]*sw_k[0]*wcf_k[0] + w_k[1]*sw_k[1]*wcf_k[1];
    float cwsp = w_k[0] + w_k[1];
    float sump = sw_k[0] + sw_k[1];
    float nvp  = val_k[0] + val_k[1];
    num  += __shfl_xor(num, 32);
    const float cws  = cwsp + __shfl_xor(cwsp, 32) + 1e-8f;
    const float sumw = sump + __shfl_xor(sump, 32) + 1e-8f;
    const float nval = nvp + __shfl_xor(nvp, 32);

    float r1 = __builtin_amdgcn_rcpf(sumw);
    r1 = r1 * (2.f - sumw * r1);
    float r2 = __builtin_amdgcn_rcpf(cws);
    r2 = r2 * (2.f - cws * r2);
    const float part = num * r1 * r2;

    const float hr = hmax - hmin;
    float rhr = __builtin_amdgcn_rcpf(hr);
    rhr = rhr * (2.f - hr * rhr);
    const float logit = part + (dep_d - hmin) * rhr;

    // ---- epilogue: attn softmax + argmax (within-half butterflies) ----
    float m = logit;
    for (int off = 1; off < 32; off <<= 1) m = fmaxf(m, __shfl_xor(m, off));
    const float e = __expf(logit - m);
    float se = e;
    for (int off = 1; off < 32; off <<= 1) se += __shfl_xor(se, off);
    float rse = __builtin_amdgcn_rcpf(se);
    rse = rse * (2.f - se * rse);
    const float attn = e * rse;

    if (wl < 32) {
        out[OFF_ATTN + wl*HWc + pix] = attn;
        out[OFF_NVAL + wl*HWc + pix] = nval;
    }

    float av = attn; int ai = wl & 31;
    for (int off = 1; off < 32; off <<= 1) {
        float av2 = __shfl_xor(av, off);
        int ai2 = __shfl_xor(ai, off);
        if (av2 > av || (av2 == av && ai2 < ai)) { av = av2; ai = ai2; }
    }
    const float dep_sel = __shfl(dep_d, ai);
    const float dep0 = __shfl(dep_d, 0);
    const float dep1 = __shfl(dep_d, 1);
    if (wl == 0) {
        const float last_itv = dep1 - dep0;
        out[OFF_DEPTH + pix] = dep_sel;
        out[OFF_CONF + pix] = av;
        out[OFF_SW + pix] = sumw * 0.25f;   // d==0 lane, /nsrc
        out[OFF_MIN + pix] = dep_sel - last_itv;
        out[OFF_MAX + pix] = dep_sel + last_itv;
    }
    if (wl >= 32 && wl < 35) {
        const int r = wl - 32;
        float v = npv.x*w_norm[r*3+0] + npv.y*w_norm[r*3+1] + npv.z*w_norm[r*3+2];
        out[OFF_EST + r*HWc + pix] = v;
    }
}

// ---------------- fallback path (original, untransposed) ----------------
__global__ void setup_kernel_fb(const float* __restrict__ rotation,
                                const float* __restrict__ proj,
                                float* __restrict__ wsf) {
    if (threadIdx.x != 0 || blockIdx.x != 0) return;
    unsigned int* wsu = (unsigned int*)wsf;
    wsu[0] = 0x7F800000u;
    wsu[1] = 0u;
    setup_body(rotation, proj, wsf);
}

__global__ __launch_bounds__(256)
void minmax_kernel_fb(const float* __restrict__ depth, unsigned int* __restrict__ wsu) {
    const int tid = blockIdx.x * blockDim.x + threadIdx.x;
    const int stride = gridDim.x * blockDim.x;
    const int n4 = (Dc*HWc) / 4;
    const float4* d4 = (const float4*)depth;
    float mn = __uint_as_float(0x7F800000u);
    float mx = 0.f;
    for (int idx = tid; idx < n4; idx += stride) {
        float4 v = d4[idx];
        mn = fminf(mn, fminf(fminf(v.x, v.y), fminf(v.z, v.w)));
        mx = fmaxf(mx, fmaxf(fmaxf(v.x, v.y), fmaxf(v.z, v.w)));
    }
    for (int off = 32; off; off >>= 1) {
        mn = fminf(mn, __shfl_xor(mn, off));
        mx = fmaxf(mx, __shfl_xor(mx, off));
    }
    __shared__ float smn[4], smx[4];
    const int w = threadIdx.x >> 6;
    if ((threadIdx.x & 63) == 0) { smn[w] = mn; smx[w] = mx; }
    __syncthreads();
    if (threadIdx.x == 0) {
        for (int i = 1; i < 4; i++) { mn = fminf(mn, smn[i]); mx = fmaxf(mx, smx[i]); }
        atomicMin(&wsu[0], __float_as_uint(mn));
        atomicMax(&wsu[1], __float_as_uint(mx));
    }
}

__global__ __launch_bounds__(256)
void main_kernel(const float* __restrict__ ref_feature,
                 const float* __restrict__ src_features,
                 const float* __restrict__ normal_plane,
                 const float* __restrict__ depth_hypo,
                 const float* __restrict__ w_reg,
                 const float* __restrict__ w_norm,
                 const float* __restrict__ wsf,
                 float* __restrict__ out) {
    const int pix = blockIdx.x;
    const int t = threadIdx.x;
    const int d = t & 31;
    const int g = t >> 5;
    const float fxp = (float)(pix % Wc);
    const float fyp = (float)(pix / Wc);

    __shared__ float s_cf[Gc*Dc];
    __shared__ float s_valid[Dc];

    float refv[4];
#pragma unroll
    for (int j = 0; j < 4; j++) refv[j] = ref_feature[(g*4+j)*HWc + pix];
    const float np0 = normal_plane[0*HWc + pix];
    const float np1 = normal_plane[1*HWc + pix];
    const float np2 = normal_plane[2*HWc + pix];
    const float depth_d = depth_hypo[d*HWc + pix];
    const float wreg_g = w_reg[g];

    float acc_cor = 0.f;
    float cws_acc = 1e-8f;
    float sumw_acc = 1e-8f;
    float nval_acc = 0.f;

    for (int i = 0; i < NSRC; i++) {
        const float* Wv = wsf + 2 + i*15;
        const float r00=Wv[0], r01=Wv[1], r02=Wv[2];
        const float r10=Wv[3], r11=Wv[4], r12=Wv[5];
        const float r20=Wv[6], r21=Wv[7], r22=Wv[8];
        const float t0=Wv[9], t1=Wv[10], t2=Wv[11];
        const float nv0=Wv[12], nv1=Wv[13], nv2=Wv[14];

        const float b0 = r00*fxp + r01*fyp + r02;
        const float b1 = r10*fxp + r11*fyp + r12;
        const float b2 = r20*fxp + r21*fyp + r22;

        float z = b2*depth_d + t2;
        if (z == 0.f) z = 1e-9f;
        const float px = (b0*depth_d + t0) / z;
        const float py = (b1*depth_d + t1) / z;

        const float fx0 = floorf(px), fy0 = floorf(py);
        const float wx = px - fx0, wy = py - fy0;
        const float fx1 = fx0 + 1.f, fy1 = fy0 + 1.f;
        const bool ix0 = (fx0 >= 0.f) && (fx0 <= (float)(Wc-1));
        const bool ix1 = (fx1 >= 0.f) && (fx1 <= (float)(Wc-1));
        const bool iy0 = (fy0 >= 0.f) && (fy0 <= (float)(Hc-1));
        const bool iy1 = (fy1 >= 0.f) && (fy1 <= (float)(Hc-1));
        const float w00 = (1.f-wx)*(1.f-wy) * ((ix0 && iy0) ? 1.f : 0.f);
        const float w10 = wx*(1.f-wy)       * ((ix1 && iy0) ? 1.f : 0.f);
        const float w01 = (1.f-wx)*wy       * ((ix0 && iy1) ? 1.f : 0.f);
        const float w11 = wx*wy             * ((ix1 && iy1) ? 1.f : 0.f);
        const int xi0 = (int)fminf(fmaxf(fx0, 0.f), (float)(Wc-1));
        const int xi1 = (int)fminf(fmaxf(fx1, 0.f), (float)(Wc-1));
        const int yi0 = (int)fminf(fmaxf(fy0, 0.f), (float)(Hc-1));
        const int yi1 = (int)fminf(fmaxf(fy1, 0.f), (float)(Hc-1));
        const int o00 = yi0*Wc + xi0, o10 = yi0*Wc + xi1;
        const int o01 = yi1*Wc + xi0, o11 = yi1*Wc + xi1;

        const float* src = src_features + (size_t)i * Cc * HWc;
        float corfeat = 0.f;
        float warp0 = 0.f;
#pragma unroll
        for (int j = 0; j < 4; j++) {
            const float* sc = src + (g*4 + j) * HWc;
            float v = w00*sc[o00] + w10*sc[o10] + w01*sc[o01] + w11*sc[o11];
            if (j == 0) warp0 = v;
            corfeat += v * refv[j];
        }
        corfeat *= 0.25f;

        s_cf[t] = corfeat;
        if (g == 0) s_valid[d] = (warp0 != 0.f) ? 1.f : 0.f;
        __syncthreads();

        float s_d = 0.f;
#pragma unroll
        for (int gg = 0; gg < Gc; gg++) s_d += s_cf[gg*32 + d];
        float m = s_d;
        for (int off = 1; off < 32; off <<= 1) m = fmaxf(m, __shfl_xor(m, off));
        float e = expf(s_d - m);
        float se = e;
        for (int off = 1; off < 32; off <<= 1) se += __shfl_xor(se, off);
        const float cor_w = (e / se) * 0.17677669529663687f;

        const float valid = s_valid[d];
        const float src_w = fmaxf(np0*nv0 + np1*nv1 + np2*nv2, 0.f) + 0.01f;
        const float sw = src_w * valid;

        acc_cor += cor_w * sw * corfeat;
        cws_acc += cor_w;
        sumw_acc += sw;
        nval_acc += valid;

        float ssum = sw;
        for (int off = 1; off < 32; off <<= 1) ssum += __shfl_xor(ssum, off);
        if (t == 0) out[OFF_WEIGHT + i*HWc + pix] = ssum * (1.f/32.f);
        __syncthreads();
    }

    const float cf_final = acc_cor / sumw_acc / cws_acc;
    s_cf[t] = cf_final * wreg_g;
    __syncthreads();
    float logit = 0.f;
#pragma unroll
    for (int gg = 0; gg < Gc; gg++) logit += s_cf[gg*32 + d];

    const unsigned int* wsu = (const unsigned int*)wsf;
    const float hmin = __uint_as_float(wsu[0]);
    const float hmax = __uint_as_float(wsu[1]);
    logit += (depth_d - hmin) / (hmax - hmin);

    float m = logit;
    for (int off = 1; off < 32; off <<= 1) m = fmaxf(m, __shfl_xor(m, off));
    float e = expf(logit - m);
    float se = e;
    for (int off = 1; off < 32; off <<= 1) se += __shfl_xor(se, off);
    const float attn = e / se;

    float av = attn; int ai = d;
    for (int off = 1; off < 32; off <<= 1) {
        float av2 = __shfl_xor(av, off);
        int ai2 = __shfl_xor(ai, off);
        if (av2 > av || (av2 == av && ai2 < ai)) { av = av2; ai = ai2; }
    }
    const float dep_sel = __shfl(depth_d, ai, 32);
    const float dep0 = __shfl(depth_d, 0, 32);
    const float dep1 = __shfl(depth_d, 1, 32);
    const float last_itv = dep1 - dep0;

    if (t < 32) {
        out[OFF_ATTN + d*HWc + pix] = attn;
        out[OFF_NVAL + d*HWc + pix] = nval_acc;
    }
    if (t == 0) {
        out[OFF_DEPTH + pix] = dep_sel;
        out[OFF_CONF + pix] = av;
        out[OFF_SW + pix] = sumw_acc * 0.25f;
        out[OFF_MIN + pix] = dep_sel - last_itv;
        out[OFF_MAX + pix] = dep_sel + last_itv;
    }
    if (t < 3) {
        float v = np0*w_norm[t*3+0] + np1*w_norm[t*3+1] + np2*w_norm[t*3+2];
        out[OFF_EST + t*HWc + pix] = v;
    }
}

extern "C" void kernel_launch(void* const* d_in, const int* in_sizes, int n_in,
                              void* d_out, int out_size, void* d_ws, size_t ws_size,
                              hipStream_t stream) {
    const float* ref   = (const float*)d_in[0];
    const float* src   = (const float*)d_in[1];
    const float* rot   = (const float*)d_in[2];
    const float* np_   = (const float*)d_in[3];
    const float* proj  = (const float*)d_in[4];
    const float* dh    = (const float*)d_in[5];
    const float* wreg  = (const float*)d_in[6];
    const float* wnorm = (const float*)d_in[7];
    float* out = (float*)d_out;
    float* ws  = (float*)d_ws;

    const size_t need_np   = (size_t)(NP_OFF + 4*HWc) * sizeof(float);
    const size_t need_base = (size_t)NP_OFF * sizeof(float);

    if (ws_size >= need_np) {
        dim3 tg(NTILE, 7);
        prep_kernel<<<tg, 256, 0, stream>>>(src, ref, dh, np_, rot, proj, ws);
        reduce_kernel<<<1, 256, 0, stream>>>(ws);
        main_kernel_t<true><<<HWc/4, 256, 0, stream>>>(np_, wreg, wnorm, ws, out);
    } else if (ws_size >= need_base) {
        dim3 tg(NTILE, 6);
        prep_kernel<<<tg, 256, 0, stream>>>(src, ref, dh, np_, rot, proj, ws);
        reduce_kernel<<<1, 256, 0, stream>>>(ws);
        main_kernel_t<false><<<HWc/4, 256, 0, stream>>>(np_, wreg, wnorm, ws, out);
    } else {
        hipMemsetAsync((char*)d_ws + 0, 0xFF, 4, stream);
        hipMemsetAsync((char*)d_ws + 4, 0x00, 4, stream);
        setup_kernel_fb<<<1, 1, 0, stream>>>(rot, proj, ws);
        minmax_kernel_fb<<<64, 256, 0, stream>>>(dh, (unsigned int*)ws);
        main_kernel<<<HWc, 256, 0, stream>>>(ref, src, np_, dh, wreg, wnorm, ws, out);
    }
}